// Round 3
// baseline (9771.758 us; speedup 1.0000x reference)
//
#include <hip/hip_runtime.h>
#include <math.h>

// Problem constants
#define NPTS   131072      // RN*SN = 1024*128
#define NVIEW  4
#define IMH    256
#define IMW    256

// Workspace layout (float offsets)
#define WS_FEATT   0u
#define WS_IMGT    8388608u
#define WS_X1      9437184u
#define WS_XR      26214400u
#define WS_MSG     31457280u
#define WS_RGB     36700160u
#define WS_DIR     38273024u
#define WS_MASK    39845888u

__device__ __forceinline__ float elup1(float t) { return t > 0.f ? t + 1.f : expf(t); }

// ---------------------------------------------------------------------------
// K0: (v,c,y,x) -> (v,y,x,c) transpose for feat (32ch) and rgb (3ch, padded 4)
// ---------------------------------------------------------------------------
__global__ __launch_bounds__(256) void k0_transpose(
    const float* __restrict__ feat, const float* __restrict__ img,
    float* __restrict__ featT, float* __restrict__ imgT)
{
    int tid = blockIdx.x * 256 + threadIdx.x;
    int v = tid >> 16, pix = tid & 65535;
    float buf[32];
#pragma unroll
    for (int c = 0; c < 32; ++c)
        buf[c] = feat[((size_t)(v * 32 + c) << 16) + pix];
    float4* dst = (float4*)(featT + ((size_t)tid << 5));
#pragma unroll
    for (int q = 0; q < 8; ++q)
        dst[q] = make_float4(buf[4*q], buf[4*q+1], buf[4*q+2], buf[4*q+3]);
    float4 rgb;
    rgb.x = img[((size_t)(v * 3 + 0) << 16) + pix];
    rgb.y = img[((size_t)(v * 3 + 1) << 16) + pix];
    rgb.z = img[((size_t)(v * 3 + 2) << 16) + pix];
    rgb.w = 0.f;
    *(float4*)(imgT + ((size_t)tid << 2)) = rgb;
}

// ---------------------------------------------------------------------------
// K1: per (point, view): geometry + bilinear sample (unchanged)
// ---------------------------------------------------------------------------
__global__ __launch_bounds__(256) void k1_geom_sample(
    const float* __restrict__ p3d, const float* __restrict__ rpi,
    const float* __restrict__ spi, const float* __restrict__ sp,
    const float* __restrict__ featT, const float* __restrict__ imgT,
    float* __restrict__ x1, float* __restrict__ rgbw,
    float* __restrict__ dirw, float* __restrict__ maskw,
    float* __restrict__ outpip)
{
    int tid = blockIdx.x * 256 + threadIdx.x;
    int p = tid >> 2, v = tid & 3;
    float X = p3d[p * 3 + 0], Y = p3d[p * 3 + 1], Z = p3d[p * 3 + 2];

    float a0 = X - rpi[3], a1 = Y - rpi[7], a2 = Z - rpi[11];
    float na = sqrtf(a0 * a0 + a1 * a1 + a2 * a2);
    a0 /= na; a1 /= na; a2 /= na;
    const float* sv = spi + v * 16;
    float b0 = X - sv[3], b1 = Y - sv[7], b2 = Z - sv[11];
    float nb = sqrtf(b0 * b0 + b1 * b1 + b2 * b2);
    b0 /= nb; b1 /= nb; b2 /= nb;
    dirw[(size_t)p * 12 + v * 3 + 0] = a0 - b0;
    dirw[(size_t)p * 12 + v * 3 + 1] = a1 - b1;
    dirw[(size_t)p * 12 + v * 3 + 2] = a2 - b2;

    const float* P = sp + v * 16;
    float pip0 = P[0] * X + P[1] * Y + P[2]  * Z + P[3];
    float pip1 = P[4] * X + P[5] * Y + P[6]  * Z + P[7];
    float pip2 = P[8] * X + P[9] * Y + P[10] * Z + P[11];
    outpip[(size_t)(v * 3 + 0) * NPTS + p] = pip0;
    outpip[(size_t)(v * 3 + 1) * NPTS + p] = pip1;
    outpip[(size_t)(v * 3 + 2) * NPTS + p] = pip2;

    float gx = pip0 / pip2, gy = pip1 / pip2;
    float inb = (gx >= 0.f && gx <= 255.f && gy >= 0.f && gy <= 255.f) ? 1.f : 0.f;
    float mvd = pip2 > 0.f ? 1.f : 0.f;
    maskw[(size_t)p * 4 + v] = inb * mvd;

    float x0f = floorf(gx), y0f = floorf(gy);
    float wx = gx - x0f, wy = gy - y0f;
    int ix0 = (int)x0f, iy0 = (int)y0f;
    float tw[4] = { (1.f-wx)*(1.f-wy), wx*(1.f-wy), (1.f-wx)*wy, wx*wy };
    int tdx[4] = { 0, 1, 0, 1 };
    int tdy[4] = { 0, 0, 1, 1 };

    float facc[32];
#pragma unroll
    for (int c = 0; c < 32; ++c) facc[c] = 0.f;
    float r0 = 0.f, r1 = 0.f, r2 = 0.f;

#pragma unroll
    for (int tno = 0; tno < 4; ++tno) {
        int ix = ix0 + tdx[tno], iy = iy0 + tdy[tno];
        float valid = (ix >= 0 && ix < IMW && iy >= 0 && iy < IMH) ? 1.f : 0.f;
        int cx = min(max(ix, 0), IMW - 1), cy = min(max(iy, 0), IMH - 1);
        float wgt = tw[tno] * valid;
        size_t base = ((size_t)v << 16) + ((size_t)cy << 8) + (size_t)cx;
        const float4* fp = (const float4*)(featT + base * 32);
#pragma unroll
        for (int q = 0; q < 8; ++q) {
            float4 f4 = fp[q];
            facc[4*q+0] += f4.x * wgt; facc[4*q+1] += f4.y * wgt;
            facc[4*q+2] += f4.z * wgt; facc[4*q+3] += f4.w * wgt;
        }
        float4 rp = *(const float4*)(imgT + base * 4);
        r0 += rp.x * wgt; r1 += rp.y * wgt; r2 += rp.z * wgt;
    }

    float4* xd = (float4*)(x1 + ((size_t)p * 4 + v) * 32);
#pragma unroll
    for (int q = 0; q < 8; ++q)
        xd[q] = make_float4(facc[4*q], facc[4*q+1], facc[4*q+2], facc[4*q+3]);
    rgbw[(size_t)p * 12 + v * 3 + 0] = r0;
    rgbw[(size_t)p * 12 + v * 3 + 1] = r1;
    rgbw[(size_t)p * 12 + v * 3 + 2] = r2;
}

// ---------------------------------------------------------------------------
// K2 v7: T=2 points per thread. k2 is LDS-instruction-throughput bound on
// broadcast weight reads (~2560 ds_read_b128/wave/group); each weight value
// is now loaded ONCE and applied to 2 tokens -> DS instr per token halved.
// Register discipline (compiler caps this kernel at 128 VGPR for big blocks,
// spilling beyond is catastrophic - 24 GB scratch in v5/v6):
//   - max 2x32 accumulators live per phase (K/V, attn, FFN)
//   - msg staged through same-thread LDS slots (16B lane stride, no conflicts)
//   - FFN in 16-column quarters: hacc 2x16 + oacc 2x32 = 96 live
//   - x re-read from global per phase (L1-hot), NOT register-hoisted
// BLK=256: 43 pairs x 5 tokens = 215 active. LDS = 41.5K weights +
// 430 rows * 68f = 116.9K -> 158.4 KB, 1 block/CU. 3 barriers/group.
// ---------------------------------------------------------------------------
#define K2_BLK    256
#define K2_PTS    86
#define K2_PAIRS  43
#define K2_ACT    215                              // 43*5
#define K2_ROWS   (K2_PTS * 5)                     // 430
#define K2_GRID   256
#define K2_NGRP   ((NPTS + K2_PTS - 1) / K2_PTS)   // 1525

// weight LDS offsets (floats)
#define WQo   0
#define WKo   1024
#define WVo   2048
#define WMo   3072
#define W1o   4096
#define W2o   8192
#define LNo   10240   // g1[32] b1[32] g2[32] b2[32]

// dual-token fma: each weight loaded once, applied to both tokens
__device__ __forceinline__ void fma4x2(const float4 a, const float4 b,
                                       const float* __restrict__ w, const int stride,
                                       float* __restrict__ accA, float* __restrict__ accB)
{
#pragma unroll
    for (int j = 0; j < 32; ++j) { float w0 = w[j];            accA[j] = fmaf(a.x, w0, accA[j]); accB[j] = fmaf(b.x, w0, accB[j]); }
#pragma unroll
    for (int j = 0; j < 32; ++j) { float w0 = w[stride + j];   accA[j] = fmaf(a.y, w0, accA[j]); accB[j] = fmaf(b.y, w0, accB[j]); }
#pragma unroll
    for (int j = 0; j < 32; ++j) { float w0 = w[2*stride + j]; accA[j] = fmaf(a.z, w0, accA[j]); accB[j] = fmaf(b.z, w0, accB[j]); }
#pragma unroll
    for (int j = 0; j < 32; ++j) { float w0 = w[3*stride + j]; accA[j] = fmaf(a.w, w0, accA[j]); accB[j] = fmaf(b.w, w0, accB[j]); }
}

__device__ __forceinline__ void fma4x2_16(const float4 a, const float4 b,
                                          const float* __restrict__ w, const int stride,
                                          float* __restrict__ accA, float* __restrict__ accB)
{
#pragma unroll
    for (int j = 0; j < 16; ++j) { float w0 = w[j];            accA[j] = fmaf(a.x, w0, accA[j]); accB[j] = fmaf(b.x, w0, accB[j]); }
#pragma unroll
    for (int j = 0; j < 16; ++j) { float w0 = w[stride + j];   accA[j] = fmaf(a.y, w0, accA[j]); accB[j] = fmaf(b.y, w0, accB[j]); }
#pragma unroll
    for (int j = 0; j < 16; ++j) { float w0 = w[2*stride + j]; accA[j] = fmaf(a.z, w0, accA[j]); accB[j] = fmaf(b.z, w0, accB[j]); }
#pragma unroll
    for (int j = 0; j < 16; ++j) { float w0 = w[3*stride + j]; accA[j] = fmaf(a.w, w0, accA[j]); accB[j] = fmaf(b.w, w0, accB[j]); }
}

__global__ __launch_bounds__(K2_BLK) void k2_loftr1(
    float* __restrict__ x1g, const float* __restrict__ vtok,
    const float* __restrict__ Wq, const float* __restrict__ Wk,
    const float* __restrict__ Wv, const float* __restrict__ Wm,
    const float* __restrict__ g1v, const float* __restrict__ b1v,
    const float* __restrict__ W1, const float* __restrict__ W2,
    const float* __restrict__ g2v, const float* __restrict__ b2v,
    float* __restrict__ xr)
{
    __shared__ float wsm[10368];           // all weights, persistent (41.5 KB)
    __shared__ float shr[K2_ROWS * 68];    // K/V rows; msg slots overlay after attn

    int t = threadIdx.x;
    // ---- one-time cooperative weight load
    for (int i = t; i < 1024; i += K2_BLK) {
        wsm[WQo + i] = Wq[i]; wsm[WKo + i] = Wk[i];
        wsm[WVo + i] = Wv[i]; wsm[WMo + i] = Wm[i];
    }
    for (int i = t; i < 4096; i += K2_BLK) wsm[W1o + i] = W1[i];
    for (int i = t; i < 2048; i += K2_BLK) wsm[W2o + i] = W2[i];
    if (t < 32) {
        wsm[LNo + t] = g1v[t]; wsm[LNo + 32 + t] = b1v[t];
        wsm[LNo + 64 + t] = g2v[t]; wsm[LNo + 96 + t] = b2v[t];
    }
    __syncthreads();

    bool act = (t < K2_ACT);
    int pair = act ? t / 5 : 0;
    int l    = act ? t - pair * 5 : 0;
    const int plA = pair * 2, plB = pair * 2 + 1;

    for (int grp = blockIdx.x; grp < K2_NGRP; grp += gridDim.x) {
        int pA = grp * K2_PTS + plA;
        int pB = pA + 1;
        bool validA = act && (pA < NPTS);
        bool validB = act && (pB < NPTS);
        int pldA = pA < NPTS ? pA : NPTS - 1;
        int pldB = pB < NPTS ? pB : NPTS - 1;
        const float4* xA = (l == 0) ? (const float4*)vtok
                                    : (const float4*)(x1g + ((size_t)pldA * 4 + (l - 1)) * 32);
        const float4* xB = (l == 0) ? (const float4*)vtok
                                    : (const float4*)(x1g + ((size_t)pldB * 4 + (l - 1)) * 32);

        __syncthreads();   // prior group's msg-slot reads complete (region reuse)

        if (act) {
            // ---- K = elup1(x @ Wk) for both points
            {
                float a0[32], a1[32];
#pragma unroll
                for (int j = 0; j < 32; ++j) { a0[j] = 0.f; a1[j] = 0.f; }
#pragma unroll
                for (int g = 0; g < 8; ++g)
                    fma4x2(xA[g], xB[g], &wsm[WKo + g * 128], 32, a0, a1);
                float* krA = &shr[(plA * 5 + l) * 68];
                float* krB = &shr[(plB * 5 + l) * 68];
#pragma unroll
                for (int j = 0; j < 32; j += 4) {
                    *(float4*)&krA[j] = make_float4(elup1(a0[j]), elup1(a0[j+1]),
                                                    elup1(a0[j+2]), elup1(a0[j+3]));
                    *(float4*)&krB[j] = make_float4(elup1(a1[j]), elup1(a1[j+1]),
                                                    elup1(a1[j+2]), elup1(a1[j+3]));
                }
            }
            // ---- V = x @ Wv for both points
            {
                float a0[32], a1[32];
#pragma unroll
                for (int j = 0; j < 32; ++j) { a0[j] = 0.f; a1[j] = 0.f; }
#pragma unroll
                for (int g = 0; g < 8; ++g)
                    fma4x2(xA[g], xB[g], &wsm[WVo + g * 128], 32, a0, a1);
                float* vrA = &shr[(plA * 5 + l) * 68 + 32];
                float* vrB = &shr[(plB * 5 + l) * 68 + 32];
#pragma unroll
                for (int j = 0; j < 32; j += 4) {
                    *(float4*)&vrA[j] = make_float4(a0[j], a0[j+1], a0[j+2], a0[j+3]);
                    *(float4*)&vrB[j] = make_float4(a1[j], a1[j+1], a1[j+2], a1[j+3]);
                }
            }
        }
        __syncthreads();   // K/V rows visible

        float mA[32], mB[32];
        if (act) {
            // ---- attention fused with Wm for both tokens
#pragma unroll
            for (int j = 0; j < 32; ++j) { mA[j] = 0.f; mB[j] = 0.f; }
            for (int h = 0; h < 8; ++h) {
                // Q head h for both tokens (weights loaded once)
                float qa0 = 0.f, qa1 = 0.f, qa2 = 0.f, qa3 = 0.f;
                float qb0 = 0.f, qb1 = 0.f, qb2 = 0.f, qb3 = 0.f;
#pragma unroll
                for (int g = 0; g < 8; ++g) {
                    float4 va = xA[g], vb = xB[g];
                    const float* w = &wsm[WQo + g * 128 + h * 4];
                    float w0;
                    w0 = w[0];  qa0 = fmaf(va.x, w0, qa0); qb0 = fmaf(vb.x, w0, qb0);
                    w0 = w[1];  qa1 = fmaf(va.x, w0, qa1); qb1 = fmaf(vb.x, w0, qb1);
                    w0 = w[2];  qa2 = fmaf(va.x, w0, qa2); qb2 = fmaf(vb.x, w0, qb2);
                    w0 = w[3];  qa3 = fmaf(va.x, w0, qa3); qb3 = fmaf(vb.x, w0, qb3);
                    w0 = w[32]; qa0 = fmaf(va.y, w0, qa0); qb0 = fmaf(vb.y, w0, qb0);
                    w0 = w[33]; qa1 = fmaf(va.y, w0, qa1); qb1 = fmaf(vb.y, w0, qb1);
                    w0 = w[34]; qa2 = fmaf(va.y, w0, qa2); qb2 = fmaf(vb.y, w0, qb2);
                    w0 = w[35]; qa3 = fmaf(va.y, w0, qa3); qb3 = fmaf(vb.y, w0, qb3);
                    w0 = w[64]; qa0 = fmaf(va.z, w0, qa0); qb0 = fmaf(vb.z, w0, qb0);
                    w0 = w[65]; qa1 = fmaf(va.z, w0, qa1); qb1 = fmaf(vb.z, w0, qb1);
                    w0 = w[66]; qa2 = fmaf(va.z, w0, qa2); qb2 = fmaf(vb.z, w0, qb2);
                    w0 = w[67]; qa3 = fmaf(va.z, w0, qa3); qb3 = fmaf(vb.z, w0, qb3);
                    w0 = w[96]; qa0 = fmaf(va.w, w0, qa0); qb0 = fmaf(vb.w, w0, qb0);
                    w0 = w[97]; qa1 = fmaf(va.w, w0, qa1); qb1 = fmaf(vb.w, w0, qb1);
                    w0 = w[98]; qa2 = fmaf(va.w, w0, qa2); qb2 = fmaf(vb.w, w0, qb2);
                    w0 = w[99]; qa3 = fmaf(va.w, w0, qa3); qb3 = fmaf(vb.w, w0, qb3);
                }
                qa0 = elup1(qa0); qa1 = elup1(qa1); qa2 = elup1(qa2); qa3 = elup1(qa3);
                qb0 = elup1(qb0); qb1 = elup1(qb1); qb2 = elup1(qb2); qb3 = elup1(qb3);

                float oA0, oA1, oA2, oA3, oB0, oB1, oB2, oB3;
#pragma unroll
                for (int tok = 0; tok < 2; ++tok) {
                    const int pl = (tok == 0) ? plA : plB;
                    const float q0 = (tok == 0) ? qa0 : qb0;
                    const float q1 = (tok == 0) ? qa1 : qb1;
                    const float q2 = (tok == 0) ? qa2 : qb2;
                    const float q3 = (tok == 0) ? qa3 : qb3;
                    float kvm[16] = {0,0,0,0,0,0,0,0,0,0,0,0,0,0,0,0};
                    float ks0 = 0.f, ks1 = 0.f, ks2 = 0.f, ks3 = 0.f;
#pragma unroll
                    for (int l2 = 0; l2 < 5; ++l2) {
                        const float* row = &shr[(pl * 5 + l2) * 68 + h * 4];
                        float4 K4 = *(const float4*)row;
                        float4 V4 = *(const float4*)(row + 32);
                        kvm[0]  = fmaf(K4.x, V4.x, kvm[0]);  kvm[1]  = fmaf(K4.x, V4.y, kvm[1]);
                        kvm[2]  = fmaf(K4.x, V4.z, kvm[2]);  kvm[3]  = fmaf(K4.x, V4.w, kvm[3]);
                        kvm[4]  = fmaf(K4.y, V4.x, kvm[4]);  kvm[5]  = fmaf(K4.y, V4.y, kvm[5]);
                        kvm[6]  = fmaf(K4.y, V4.z, kvm[6]);  kvm[7]  = fmaf(K4.y, V4.w, kvm[7]);
                        kvm[8]  = fmaf(K4.z, V4.x, kvm[8]);  kvm[9]  = fmaf(K4.z, V4.y, kvm[9]);
                        kvm[10] = fmaf(K4.z, V4.z, kvm[10]); kvm[11] = fmaf(K4.z, V4.w, kvm[11]);
                        kvm[12] = fmaf(K4.w, V4.x, kvm[12]); kvm[13] = fmaf(K4.w, V4.y, kvm[13]);
                        kvm[14] = fmaf(K4.w, V4.z, kvm[14]); kvm[15] = fmaf(K4.w, V4.w, kvm[15]);
                        ks0 += K4.x; ks1 += K4.y; ks2 += K4.z; ks3 += K4.w;
                    }
                    float den = 1e-6f + q0*ks0 + q1*ks1 + q2*ks2 + q3*ks3;
                    float inv = 1.f / den;
                    float o0 = (q0*kvm[0] + q1*kvm[4] + q2*kvm[8]  + q3*kvm[12]) * inv;
                    float o1 = (q0*kvm[1] + q1*kvm[5] + q2*kvm[9]  + q3*kvm[13]) * inv;
                    float o2 = (q0*kvm[2] + q1*kvm[6] + q2*kvm[10] + q3*kvm[14]) * inv;
                    float o3 = (q0*kvm[3] + q1*kvm[7] + q2*kvm[11] + q3*kvm[15]) * inv;
                    if (tok == 0) { oA0 = o0; oA1 = o1; oA2 = o2; oA3 = o3; }
                    else          { oB0 = o0; oB1 = o1; oB2 = o2; oB3 = o3; }
                }

                // Wm apply, weights loaded once for both tokens
                const float* wm = &wsm[WMo + h * 128];
#pragma unroll
                for (int j = 0; j < 32; ++j) { float w0 = wm[j];      mA[j] = fmaf(oA0, w0, mA[j]); mB[j] = fmaf(oB0, w0, mB[j]); }
#pragma unroll
                for (int j = 0; j < 32; ++j) { float w0 = wm[32 + j]; mA[j] = fmaf(oA1, w0, mA[j]); mB[j] = fmaf(oB1, w0, mB[j]); }
#pragma unroll
                for (int j = 0; j < 32; ++j) { float w0 = wm[64 + j]; mA[j] = fmaf(oA2, w0, mA[j]); mB[j] = fmaf(oB2, w0, mB[j]); }
#pragma unroll
                for (int j = 0; j < 32; ++j) { float w0 = wm[96 + j]; mA[j] = fmaf(oA3, w0, mA[j]); mB[j] = fmaf(oB3, w0, mB[j]); }
            }

            // ---- LN1 in place for both tokens
#pragma unroll
            for (int tok = 0; tok < 2; ++tok) {
                float* m = (tok == 0) ? mA : mB;
                float s1 = 0.f, s2 = 0.f;
#pragma unroll
                for (int j = 0; j < 32; ++j) { s1 += m[j]; s2 += m[j] * m[j]; }
                float mu = s1 * (1.f / 32.f);
                float va = s2 * (1.f / 32.f) - mu * mu;
                float rs = rsqrtf(va + 1e-5f);
#pragma unroll
                for (int j = 0; j < 32; ++j)
                    m[j] = (m[j] - mu) * rs * wsm[LNo + j] + wsm[LNo + 32 + j];
            }
        }
        __syncthreads();   // all attention reads of rows done; region becomes slots

        if (act) {
            // ---- stage msg to same-thread slots (frees mA/mB registers)
#pragma unroll
            for (int g = 0; g < 8; ++g) {
                *(float4*)&shr[((g * 2 + 0) * K2_ACT + t) * 4] =
                    make_float4(mA[4*g], mA[4*g+1], mA[4*g+2], mA[4*g+3]);
                *(float4*)&shr[((g * 2 + 1) * K2_ACT + t) * 4] =
                    make_float4(mB[4*g], mB[4*g+1], mB[4*g+2], mB[4*g+3]);
            }

            // ---- FFN in 16-column quarters (hacc 2x16 + oacc 2x32 live)
            float oA[32], oB[32];
#pragma unroll
            for (int j = 0; j < 32; ++j) { oA[j] = 0.f; oB[j] = 0.f; }
#pragma unroll
            for (int q4 = 0; q4 < 4; ++q4) {
                const int j0 = q4 * 16;
                float hA[16], hB[16];
#pragma unroll
                for (int j = 0; j < 16; ++j) { hA[j] = 0.f; hB[j] = 0.f; }
#pragma unroll
                for (int g = 0; g < 8; ++g)                  // x part (rows 0..31)
                    fma4x2_16(xA[g], xB[g], &wsm[W1o + (g * 4) * 64 + j0], 64, hA, hB);
#pragma unroll
                for (int g = 0; g < 8; ++g) {                // msg part (rows 32..63)
                    float4 ma = *(const float4*)&shr[((g * 2 + 0) * K2_ACT + t) * 4];
                    float4 mb = *(const float4*)&shr[((g * 2 + 1) * K2_ACT + t) * 4];
                    fma4x2_16(ma, mb, &wsm[W1o + (32 + g * 4) * 64 + j0], 64, hA, hB);
                }
#pragma unroll
                for (int j = 0; j < 16; ++j) { hA[j] = fmaxf(hA[j], 0.f); hB[j] = fmaxf(hB[j], 0.f); }
#pragma unroll
                for (int u = 0; u < 4; ++u) {                // W2 rows j0+4u..j0+4u+3
                    float4 ha = make_float4(hA[4*u], hA[4*u+1], hA[4*u+2], hA[4*u+3]);
                    float4 hb = make_float4(hB[4*u], hB[4*u+1], hB[4*u+2], hB[4*u+3]);
                    fma4x2(ha, hb, &wsm[W2o + (j0 + u * 4) * 32], 32, oA, oB);
                }
            }

            // ---- LN2, residual fused into stores, per token
#pragma unroll
            for (int tok = 0; tok < 2; ++tok) {
                float* o = (tok == 0) ? oA : oB;
                bool vld = (tok == 0) ? validA : validB;
                int  p   = (tok == 0) ? pA : pB;
                const float4* xs = (tok == 0) ? xA : xB;
                float s1 = 0.f, s2 = 0.f;
#pragma unroll
                for (int j = 0; j < 32; ++j) { s1 += o[j]; s2 += o[j] * o[j]; }
                float mu = s1 * (1.f / 32.f);
                float va = s2 * (1.f / 32.f) - mu * mu;
                float rs = rsqrtf(va + 1e-5f);
                if (vld) {
                    float4* dst = (l == 0) ? (float4*)(xr + (size_t)p * 40)
                                           : (float4*)(x1g + ((size_t)p * 4 + (l - 1)) * 32);
#pragma unroll
                    for (int g = 0; g < 8; ++g) {
                        float4 x4 = xs[g];
                        float4 o4;
                        o4.x = x4.x + (o[4*g+0] - mu) * rs * wsm[LNo + 64 + 4*g+0] + wsm[LNo + 96 + 4*g+0];
                        o4.y = x4.y + (o[4*g+1] - mu) * rs * wsm[LNo + 64 + 4*g+1] + wsm[LNo + 96 + 4*g+1];
                        o4.z = x4.z + (o[4*g+2] - mu) * rs * wsm[LNo + 64 + 4*g+2] + wsm[LNo + 96 + 4*g+2];
                        o4.w = x4.w + (o[4*g+3] - mu) * rs * wsm[LNo + 64 + 4*g+3] + wsm[LNo + 96 + 4*g+3];
                        dst[g] = o4;
                    }
                    if (l == 0) {
                        int sidx = p & 127;
#pragma unroll
                        for (int c = 0; c < 8; ++c) {
                            float den = (c < 2) ? 1.f : (c < 4) ? 10.f : (c < 6) ? 100.f : 1000.f;
                            float arg = (float)sidx / den;
                            xr[(size_t)p * 40 + 32 + c] = (c & 1) ? cosf(arg) : sinf(arg);
                        }
                    }
                }
            }
        }
    }
}

// ---------------------------------------------------------------------------
// K3a: layer-2 attention half (unchanged)
// ---------------------------------------------------------------------------
__global__ __launch_bounds__(320) void k3a_attn(
    const float* __restrict__ xr,
    const float* __restrict__ Wq, const float* __restrict__ Wk,
    const float* __restrict__ Wv, const float* __restrict__ Wm,
    const float* __restrict__ g1, const float* __restrict__ b1,
    float* __restrict__ msg)
{
    __shared__ float kb[5120];
    __shared__ float vb[5120];
    __shared__ float wb[1600];
    __shared__ float kvb[200];
    __shared__ float ksb[40];
    int t = threadIdx.x, r = blockIdx.x;
    const float* xbase = xr + (size_t)r * 5120;
    int lg = t / 40, c = t % 40;

    for (int i = t; i < 1600; i += 320) wb[i] = Wk[i];
    __syncthreads();
    {
        float acc[16];
#pragma unroll
        for (int i = 0; i < 16; ++i) acc[i] = 0.f;
        for (int kk = 0; kk < 40; ++kk) {
            float w = wb[kk * 40 + c];
#pragma unroll
            for (int i = 0; i < 16; ++i) acc[i] += xbase[(lg * 16 + i) * 40 + kk] * w;
        }
#pragma unroll
        for (int i = 0; i < 16; ++i) kb[(lg * 16 + i) * 40 + c] = elup1(acc[i]);
    }
    __syncthreads();
    for (int i = t; i < 1600; i += 320) wb[i] = Wv[i];
    __syncthreads();
    {
        float acc[16];
#pragma unroll
        for (int i = 0; i < 16; ++i) acc[i] = 0.f;
        for (int kk = 0; kk < 40; ++kk) {
            float w = wb[kk * 40 + c];
#pragma unroll
            for (int i = 0; i < 16; ++i) acc[i] += xbase[(lg * 16 + i) * 40 + kk] * w;
        }
#pragma unroll
        for (int i = 0; i < 16; ++i) vb[(lg * 16 + i) * 40 + c] = acc[i];
    }
    __syncthreads();
    if (t < 200) {
        int h = t / 25, e = (t / 5) % 5, d = t % 5;
        float kv = 0.f, ks = 0.f;
        for (int s2 = 0; s2 < 128; ++s2) {
            float kvv = kb[s2 * 40 + h * 5 + e];
            float vv  = vb[s2 * 40 + h * 5 + d];
            kv += kvv * vv; ks += kvv;
        }
        kvb[t] = kv;
        if (d == 0) ksb[h * 5 + e] = ks;
    }
    __syncthreads();
    for (int i = t; i < 1600; i += 320) wb[i] = Wq[i];
    __syncthreads();
    {
        float acc[16];
#pragma unroll
        for (int i = 0; i < 16; ++i) acc[i] = 0.f;
        for (int kk = 0; kk < 40; ++kk) {
            float w = wb[kk * 40 + c];
#pragma unroll
            for (int i = 0; i < 16; ++i) acc[i] += xbase[(lg * 16 + i) * 40 + kk] * w;
        }
#pragma unroll
        for (int i = 0; i < 16; ++i) kb[(lg * 16 + i) * 40 + c] = elup1(acc[i]);
    }
    __syncthreads();
    {
        int h = c / 5, d = c % 5;
#pragma unroll 4
        for (int i = 0; i < 16; ++i) {
            int l = lg * 16 + i;
            float den = 1e-6f, o = 0.f;
#pragma unroll
            for (int e = 0; e < 5; ++e) {
                float q = kb[l * 40 + h * 5 + e];
                den += q * ksb[h * 5 + e];
                o   += q * kvb[h * 25 + e * 5 + d];
            }
            vb[l * 40 + c] = o / den;
        }
    }
    __syncthreads();
    for (int i = t; i < 1600; i += 320) wb[i] = Wm[i];
    __syncthreads();
    {
        float acc[16];
#pragma unroll
        for (int i = 0; i < 16; ++i) acc[i] = 0.f;
        for (int kk = 0; kk < 40; ++kk) {
            float w = wb[kk * 40 + c];
#pragma unroll
            for (int i = 0; i < 16; ++i) acc[i] += vb[(lg * 16 + i) * 40 + kk] * w;
        }
#pragma unroll
        for (int i = 0; i < 16; ++i) kb[(lg * 16 + i) * 40 + c] = acc[i];
    }
    __syncthreads();
    if (t < 128) {
        float s1 = 0.f, s2v = 0.f;
        for (int j = 0; j < 40; ++j) { float x = kb[t * 40 + j]; s1 += x; s2v += x * x; }
        float m = s1 * (1.f / 40.f), va = s2v * (1.f / 40.f) - m * m;
        float rs = rsqrtf(va + 1e-5f);
        for (int j = 0; j < 40; ++j)
            msg[((size_t)r * 128 + t) * 40 + j] = (kb[t * 40 + j] - m) * rs * g1[j] + b1[j];
    }
}

// ---------------------------------------------------------------------------
// K3b: layer-2 FFN half (unchanged)
// ---------------------------------------------------------------------------
__global__ __launch_bounds__(320) void k3b_ffn(
    float* __restrict__ xr, const float* __restrict__ msg,
    const float* __restrict__ W1, const float* __restrict__ W2,
    const float* __restrict__ g2, const float* __restrict__ b2)
{
    __shared__ float hb[10240];
    __shared__ float wb[3200];
    int t = threadIdx.x, r = blockIdx.x;
    int lg = t / 40, c = t % 40;
    const float* xbase = xr + (size_t)r * 5120;
    const float* mbase = msg + (size_t)r * 5120;

    float hA[16], hB[16];
#pragma unroll
    for (int i = 0; i < 16; ++i) { hA[i] = 0.f; hB[i] = 0.f; }

    for (int i = t; i < 3200; i += 320) wb[i] = W1[i];
    __syncthreads();
    for (int kk = 0; kk < 40; ++kk) {
        float wa = wb[kk * 80 + c], wbb = wb[kk * 80 + c + 40];
#pragma unroll
        for (int i = 0; i < 16; ++i) {
            float xv = xbase[(lg * 16 + i) * 40 + kk];
            hA[i] += xv * wa; hB[i] += xv * wbb;
        }
    }
    __syncthreads();
    for (int i = t; i < 3200; i += 320) wb[i] = W1[3200 + i];
    __syncthreads();
    for (int kk = 0; kk < 40; ++kk) {
        float wa = wb[kk * 80 + c], wbb = wb[kk * 80 + c + 40];
#pragma unroll
        for (int i = 0; i < 16; ++i) {
            float mv = mbase[(lg * 16 + i) * 40 + kk];
            hA[i] += mv * wa; hB[i] += mv * wbb;
        }
    }
#pragma unroll
    for (int i = 0; i < 16; ++i) {
        hb[(lg * 16 + i) * 80 + c]      = fmaxf(hA[i], 0.f);
        hb[(lg * 16 + i) * 80 + c + 40] = fmaxf(hB[i], 0.f);
    }
    __syncthreads();
    for (int i = t; i < 3200; i += 320) wb[i] = W2[i];
    __syncthreads();
    float oa[16];
#pragma unroll
    for (int i = 0; i < 16; ++i) oa[i] = 0.f;
    for (int kk = 0; kk < 80; ++kk) {
        float w = wb[kk * 40 + c];
#pragma unroll
        for (int i = 0; i < 16; ++i) oa[i] += hb[(lg * 16 + i) * 80 + kk] * w;
    }
    __syncthreads();
#pragma unroll
    for (int i = 0; i < 16; ++i) hb[(lg * 16 + i) * 40 + c] = oa[i];
    __syncthreads();
    if (t < 128) {
        float s1 = 0.f, s2v = 0.f;
        for (int j = 0; j < 40; ++j) { float x = hb[t * 40 + j]; s1 += x; s2v += x * x; }
        float m = s1 * (1.f / 40.f), va = s2v * (1.f / 40.f) - m * m;
        float rs = rsqrtf(va + 1e-5f);
        for (int j = 0; j < 40; ++j) {
            float y = xbase[t * 40 + j] + (hb[t * 40 + j] - m) * rs * g2[j] + b2[j];
            xr[(size_t)r * 5120 + t * 40 + j] = y;
        }
    }
}

// ---------------------------------------------------------------------------
// K4: srdf head (unchanged)
// ---------------------------------------------------------------------------
__global__ __launch_bounds__(256) void k4_dm(
    const float* __restrict__ xr,
    const float* __restrict__ W1, const float* __restrict__ b1,
    const float* __restrict__ W2, const float* __restrict__ b2,
    const float* __restrict__ W3, const float* __restrict__ b3,
    float* __restrict__ out1)
{
    __shared__ float s[1857];
    int t = threadIdx.x;
    for (int i = t; i < 1280; i += 256) s[i] = W1[i];
    if (t < 32) s[1280 + t] = b1[t];
    for (int i = t; i < 512; i += 256) s[1312 + i] = W2[i];
    if (t < 16) { s[1824 + t] = b2[t]; s[1840 + t] = W3[t]; }
    if (t == 0) s[1856] = b3[0];
    __syncthreads();

    int p = blockIdx.x * 256 + t;
    float x[40];
    const float4* xp = (const float4*)(xr + (size_t)p * 40);
#pragma unroll
    for (int i = 0; i < 10; ++i) {
        float4 v4 = xp[i];
        x[4*i] = v4.x; x[4*i+1] = v4.y; x[4*i+2] = v4.z; x[4*i+3] = v4.w;
    }
    float h1[32];
#pragma unroll
    for (int j = 0; j < 32; ++j) h1[j] = s[1280 + j];
    for (int k = 0; k < 40; ++k) {
        float xv = x[k];
#pragma unroll
        for (int j = 0; j < 32; ++j) h1[j] += xv * s[k * 32 + j];
    }
#pragma unroll
    for (int j = 0; j < 32; ++j) h1[j] = fmaxf(h1[j], 0.f);
    float h2[16];
#pragma unroll
    for (int j = 0; j < 16; ++j) h2[j] = s[1824 + j];
    for (int k = 0; k < 32; ++k) {
        float hv = h1[k];
#pragma unroll
        for (int j = 0; j < 16; ++j) h2[j] += hv * s[1312 + k * 16 + j];
    }
    float o = s[1856];
#pragma unroll
    for (int j = 0; j < 16; ++j) o += fmaxf(h2[j], 0.f) * s[1840 + j];
    out1[p] = o;
}

// ---------------------------------------------------------------------------
// K5: rw head + masked softmax + radiance blend (unchanged)
// ---------------------------------------------------------------------------
__global__ __launch_bounds__(256) void k5_rw(
    const float* __restrict__ vf, const float* __restrict__ dirw,
    const float* __restrict__ maskw, const float* __restrict__ rgbw,
    const float* __restrict__ W1, const float* __restrict__ b1,
    const float* __restrict__ W2, const float* __restrict__ b2,
    const float* __restrict__ W3, const float* __restrict__ b3,
    float* __restrict__ out0)
{
    __shared__ float s[721];
    int t = threadIdx.x;
    for (int i = t; i < 560; i += 256) s[i] = W1[i];
    if (t < 16) s[560 + t] = b1[t];
    if (t < 128) s[576 + t] = W2[t];
    if (t < 8) { s[704 + t] = b2[t]; s[712 + t] = W3[t]; }
    if (t == 0) s[720] = b3[0];
    __syncthreads();

    int p = blockIdx.x * 256 + t;
    float xw[4];
#pragma unroll
    for (int v = 0; v < 4; ++v) {
        float in[35];
        const float4* vp = (const float4*)(vf + ((size_t)p * 4 + v) * 32);
#pragma unroll
        for (int q = 0; q < 8; ++q) {
            float4 f4 = vp[q];
            in[4*q] = f4.x; in[4*q+1] = f4.y; in[4*q+2] = f4.z; in[4*q+3] = f4.w;
        }
        in[32] = dirw[(size_t)p * 12 + v * 3 + 0];
        in[33] = dirw[(size_t)p * 12 + v * 3 + 1];
        in[34] = dirw[(size_t)p * 12 + v * 3 + 2];
        float h1[16];
#pragma unroll
        for (int j = 0; j < 16; ++j) h1[j] = s[560 + j];
        for (int k = 0; k < 35; ++k) {
            float xv = in[k];
#pragma unroll
            for (int j = 0; j < 16; ++j) h1[j] += xv * s[k * 16 + j];
        }
        float h2[8];
#pragma unroll
        for (int j = 0; j < 8; ++j) h2[j] = s[704 + j];
        for (int k = 0; k < 16; ++k) {
            float hv = fmaxf(h1[k], 0.f);
#pragma unroll
            for (int j = 0; j < 8; ++j) h2[j] += hv * s[576 + k * 8 + j];
        }
        float o = s[720];
#pragma unroll
        for (int j = 0; j < 8; ++j) o += fmaxf(h2[j], 0.f) * s[712 + j];
        xw[v] = (maskw[(size_t)p * 4 + v] == 0.f) ? -1e9f : o;
    }
    float m = fmaxf(fmaxf(xw[0], xw[1]), fmaxf(xw[2], xw[3]));
    float e0 = expf(xw[0] - m), e1 = expf(xw[1] - m), e2 = expf(xw[2] - m), e3 = expf(xw[3] - m);
    float inv = 1.f / (e0 + e1 + e2 + e3);
    float w4[4] = { e0 * inv, e1 * inv, e2 * inv, e3 * inv };
    float r0 = 0.f, r1 = 0.f, r2 = 0.f;
#pragma unroll
    for (int v = 0; v < 4; ++v) {
        r0 += rgbw[(size_t)p * 12 + v * 3 + 0] * w4[v];
        r1 += rgbw[(size_t)p * 12 + v * 3 + 1] * w4[v];
        r2 += rgbw[(size_t)p * 12 + v * 3 + 2] * w4[v];
    }
    out0[(size_t)p * 3 + 0] = r0;
    out0[(size_t)p * 3 + 1] = r1;
    out0[(size_t)p * 3 + 2] = r2;
}

// ---------------------------------------------------------------------------
extern "C" void kernel_launch(void* const* d_in, const int* in_sizes, int n_in,
                              void* d_out, int out_size, void* d_ws, size_t ws_size,
                              hipStream_t stream) {
    (void)in_sizes; (void)n_in; (void)out_size; (void)ws_size;
    const float* p3d   = (const float*)d_in[0];
    const float* imgs  = (const float*)d_in[1];
    const float* feat  = (const float*)d_in[2];
    const float* rpi   = (const float*)d_in[3];
    const float* spi   = (const float*)d_in[4];
    const float* sp    = (const float*)d_in[5];
    const float* vtok  = (const float*)d_in[6];
    const float* vtWq  = (const float*)d_in[7];
    const float* vtWk  = (const float*)d_in[8];
    const float* vtWv  = (const float*)d_in[9];
    const float* vtWm  = (const float*)d_in[10];
    const float* vtg1  = (const float*)d_in[11];
    const float* vtb1  = (const float*)d_in[12];
    const float* vtW1  = (const float*)d_in[13];
    const float* vtW2  = (const float*)d_in[14];
    const float* vtg2  = (const float*)d_in[15];
    const float* vtb2  = (const float*)d_in[16];
    const float* rtWq  = (const float*)d_in[17];
    const float* rtWk  = (const float*)d_in[18];
    const float* rtWv  = (const float*)d_in[19];
    const float* rtWm  = (const float*)d_in[20];
    const float* rtg1  = (const float*)d_in[21];
    const float* rtb1  = (const float*)d_in[22];
    const float* rtW1  = (const float*)d_in[23];
    const float* rtW2  = (const float*)d_in[24];
    const float* rtg2  = (const float*)d_in[25];
    const float* rtb2  = (const float*)d_in[26];
    const float* dmW1  = (const float*)d_in[27];
    const float* dmb1  = (const float*)d_in[28];
    const float* dmW2  = (const float*)d_in[29];
    const float* dmb2  = (const float*)d_in[30];
    const float* dmW3  = (const float*)d_in[31];
    const float* dmb3  = (const float*)d_in[32];
    const float* rwW1  = (const float*)d_in[33];
    const float* rwb1  = (const float*)d_in[34];
    const float* rwW2  = (const float*)d_in[35];
    const float* rwb2  = (const float*)d_in[36];
    const float* rwW3  = (const float*)d_in[37];
    const float* rwb3  = (const float*)d_in[38];

    float* out  = (float*)d_out;
    float* out0 = out;
    float* out1 = out + 393216;
    float* out2 = out + 524288;

    float* ws    = (float*)d_ws;
    float* featT = ws + WS_FEATT;
    float* imgT  = ws + WS_IMGT;
    float* x1    = ws + WS_X1;
    float* xr    = ws + WS_XR;
    float* msg   = ws + WS_MSG;
    float* rgbw  = ws + WS_RGB;
    float* dirw  = ws + WS_DIR;
    float* maskw = ws + WS_MASK;

    k0_transpose<<<dim3(1024), dim3(256), 0, stream>>>(feat, imgs, featT, imgT);
    k1_geom_sample<<<dim3(2048), dim3(256), 0, stream>>>(p3d, rpi, spi, sp, featT, imgT,
                                                         x1, rgbw, dirw, maskw, out2);
    k2_loftr1<<<dim3(K2_GRID), dim3(K2_BLK), 0, stream>>>(x1, vtok, vtWq, vtWk, vtWv, vtWm,
                                                    vtg1, vtb1, vtW1, vtW2, vtg2, vtb2, xr);
    k3a_attn<<<dim3(1024), dim3(320), 0, stream>>>(xr, rtWq, rtWk, rtWv, rtWm, rtg1, rtb1, msg);
    k3b_ffn<<<dim3(1024), dim3(320), 0, stream>>>(xr, msg, rtW1, rtW2, rtg2, rtb2);
    k4_dm<<<dim3(512), dim3(256), 0, stream>>>(xr, dmW1, dmb1, dmW2, dmb2, dmW3, dmb3, out1);
    k5_rw<<<dim3(512), dim3(256), 0, stream>>>(x1, dirw, maskw, rgbw,
                                               rwW1, rwb1, rwW2, rwb2, rwW3, rwb3, out0);
}

// Round 4
// 1130.239 us; speedup vs baseline: 8.6457x; 8.6457x over previous
//
#include <hip/hip_runtime.h>
#include <math.h>

// Problem constants
#define NPTS   131072      // RN*SN = 1024*128
#define NVIEW  4
#define IMH    256
#define IMW    256

// Workspace layout (float offsets)
#define WS_FEATT   0u
#define WS_IMGT    8388608u
#define WS_X1      9437184u
#define WS_XR      26214400u
#define WS_MSG     31457280u
#define WS_RGB     36700160u
#define WS_DIR     38273024u
#define WS_MASK    39845888u

__device__ __forceinline__ float elup1(float t) { return t > 0.f ? t + 1.f : expf(t); }

// ---------------------------------------------------------------------------
// K0: (v,c,y,x) -> (v,y,x,c) transpose for feat (32ch) and rgb (3ch, padded 4)
// ---------------------------------------------------------------------------
__global__ __launch_bounds__(256) void k0_transpose(
    const float* __restrict__ feat, const float* __restrict__ img,
    float* __restrict__ featT, float* __restrict__ imgT)
{
    int tid = blockIdx.x * 256 + threadIdx.x;
    int v = tid >> 16, pix = tid & 65535;
    float buf[32];
#pragma unroll
    for (int c = 0; c < 32; ++c)
        buf[c] = feat[((size_t)(v * 32 + c) << 16) + pix];
    float4* dst = (float4*)(featT + ((size_t)tid << 5));
#pragma unroll
    for (int q = 0; q < 8; ++q)
        dst[q] = make_float4(buf[4*q], buf[4*q+1], buf[4*q+2], buf[4*q+3]);
    float4 rgb;
    rgb.x = img[((size_t)(v * 3 + 0) << 16) + pix];
    rgb.y = img[((size_t)(v * 3 + 1) << 16) + pix];
    rgb.z = img[((size_t)(v * 3 + 2) << 16) + pix];
    rgb.w = 0.f;
    *(float4*)(imgT + ((size_t)tid << 2)) = rgb;
}

// ---------------------------------------------------------------------------
// K1: per (point, view): geometry + bilinear sample (unchanged)
// ---------------------------------------------------------------------------
__global__ __launch_bounds__(256) void k1_geom_sample(
    const float* __restrict__ p3d, const float* __restrict__ rpi,
    const float* __restrict__ spi, const float* __restrict__ sp,
    const float* __restrict__ featT, const float* __restrict__ imgT,
    float* __restrict__ x1, float* __restrict__ rgbw,
    float* __restrict__ dirw, float* __restrict__ maskw,
    float* __restrict__ outpip)
{
    int tid = blockIdx.x * 256 + threadIdx.x;
    int p = tid >> 2, v = tid & 3;
    float X = p3d[p * 3 + 0], Y = p3d[p * 3 + 1], Z = p3d[p * 3 + 2];

    float a0 = X - rpi[3], a1 = Y - rpi[7], a2 = Z - rpi[11];
    float na = sqrtf(a0 * a0 + a1 * a1 + a2 * a2);
    a0 /= na; a1 /= na; a2 /= na;
    const float* sv = spi + v * 16;
    float b0 = X - sv[3], b1 = Y - sv[7], b2 = Z - sv[11];
    float nb = sqrtf(b0 * b0 + b1 * b1 + b2 * b2);
    b0 /= nb; b1 /= nb; b2 /= nb;
    dirw[(size_t)p * 12 + v * 3 + 0] = a0 - b0;
    dirw[(size_t)p * 12 + v * 3 + 1] = a1 - b1;
    dirw[(size_t)p * 12 + v * 3 + 2] = a2 - b2;

    const float* P = sp + v * 16;
    float pip0 = P[0] * X + P[1] * Y + P[2]  * Z + P[3];
    float pip1 = P[4] * X + P[5] * Y + P[6]  * Z + P[7];
    float pip2 = P[8] * X + P[9] * Y + P[10] * Z + P[11];
    outpip[(size_t)(v * 3 + 0) * NPTS + p] = pip0;
    outpip[(size_t)(v * 3 + 1) * NPTS + p] = pip1;
    outpip[(size_t)(v * 3 + 2) * NPTS + p] = pip2;

    float gx = pip0 / pip2, gy = pip1 / pip2;
    float inb = (gx >= 0.f && gx <= 255.f && gy >= 0.f && gy <= 255.f) ? 1.f : 0.f;
    float mvd = pip2 > 0.f ? 1.f : 0.f;
    maskw[(size_t)p * 4 + v] = inb * mvd;

    float x0f = floorf(gx), y0f = floorf(gy);
    float wx = gx - x0f, wy = gy - y0f;
    int ix0 = (int)x0f, iy0 = (int)y0f;
    float tw[4] = { (1.f-wx)*(1.f-wy), wx*(1.f-wy), (1.f-wx)*wy, wx*wy };
    int tdx[4] = { 0, 1, 0, 1 };
    int tdy[4] = { 0, 0, 1, 1 };

    float facc[32];
#pragma unroll
    for (int c = 0; c < 32; ++c) facc[c] = 0.f;
    float r0 = 0.f, r1 = 0.f, r2 = 0.f;

#pragma unroll
    for (int tno = 0; tno < 4; ++tno) {
        int ix = ix0 + tdx[tno], iy = iy0 + tdy[tno];
        float valid = (ix >= 0 && ix < IMW && iy >= 0 && iy < IMH) ? 1.f : 0.f;
        int cx = min(max(ix, 0), IMW - 1), cy = min(max(iy, 0), IMH - 1);
        float wgt = tw[tno] * valid;
        size_t base = ((size_t)v << 16) + ((size_t)cy << 8) + (size_t)cx;
        const float4* fp = (const float4*)(featT + base * 32);
#pragma unroll
        for (int q = 0; q < 8; ++q) {
            float4 f4 = fp[q];
            facc[4*q+0] += f4.x * wgt; facc[4*q+1] += f4.y * wgt;
            facc[4*q+2] += f4.z * wgt; facc[4*q+3] += f4.w * wgt;
        }
        float4 rp = *(const float4*)(imgT + base * 4);
        r0 += rp.x * wgt; r1 += rp.y * wgt; r2 += rp.z * wgt;
    }

    float4* xd = (float4*)(x1 + ((size_t)p * 4 + v) * 32);
#pragma unroll
    for (int q = 0; q < 8; ++q)
        xd[q] = make_float4(facc[4*q], facc[4*q+1], facc[4*q+2], facc[4*q+3]);
    rgbw[(size_t)p * 12 + v * 3 + 0] = r0;
    rgbw[(size_t)p * 12 + v * 3 + 1] = r1;
    rgbw[(size_t)p * 12 + v * 3 + 2] = r2;
}

// ---------------------------------------------------------------------------
// K2 v8: EXACT v4 structure (the only non-spilling one: 128-thr block, row
// per thread, 24 pts/group, 3 barriers, msg/h via LDS slots) but weights are
// read DIRECTLY FROM GLOBAL with wave-uniform addresses. v4 was DS-return-
// bandwidth bound: ~2640 broadcast ds_read_b128/wave/group (~44/token,
// ~10 cyc each ≈ the whole 409 us). Uniform global reads scalarize to
// s_load (SGPR broadcast, scalar pipe) or at worst go through L1 -- either
// way off the DS pipe. DS keeps only K/V rows + msg/h slots (~6x less).
// Deleting the 41.5 KB weight LDS: 74 KB -> 32.5 KB => 4 blocks/CU,
// 8 waves/CU (was 4). Register structure untouched (no spill risk).
// ---------------------------------------------------------------------------
#define K2_BLK    128
#define K2_PTS    24
#define K2_GRID   1024
#define K2_NGRP   ((NPTS + K2_PTS - 1) / K2_PTS)   // 5462

// acc[j] += xv.{x,y,z,w} * w[u*stride + j], j=0..31  (w uniform across lanes)
__device__ __forceinline__ void fma4(const float4 xv, const float* __restrict__ w,
                                     const int stride, float* __restrict__ acc)
{
#pragma unroll
    for (int j = 0; j < 32; ++j) acc[j] = fmaf(xv.x, w[j],            acc[j]);
#pragma unroll
    for (int j = 0; j < 32; ++j) acc[j] = fmaf(xv.y, w[stride + j],   acc[j]);
#pragma unroll
    for (int j = 0; j < 32; ++j) acc[j] = fmaf(xv.z, w[2*stride + j], acc[j]);
#pragma unroll
    for (int j = 0; j < 32; ++j) acc[j] = fmaf(xv.w, w[3*stride + j], acc[j]);
}

__global__ __launch_bounds__(K2_BLK) void k2_loftr1(
    float* __restrict__ x1g, const float* __restrict__ vtok,
    const float* __restrict__ Wq, const float* __restrict__ Wk,
    const float* __restrict__ Wv, const float* __restrict__ Wm,
    const float* __restrict__ g1v, const float* __restrict__ b1v,
    const float* __restrict__ W1, const float* __restrict__ W2,
    const float* __restrict__ g2v, const float* __restrict__ b2v,
    float* __restrict__ xr)
{
    __shared__ float shr[8192];    // K/V rows | msg+h slots   (32 KB)

    int t = threadIdx.x;
    int pl = t / 5, l = t - pl * 5;
    bool act = (t < K2_PTS * 5);
    if (!act) { pl = 0; l = 0; }
    const int rowbase = (pl * 5 + l) * 68;

    for (int grp = blockIdx.x; grp < K2_NGRP; grp += gridDim.x) {
        int p = grp * K2_PTS + pl;
        bool valid = act && (p < NPTS);
        int pload = p < NPTS ? p : NPTS - 1;
        const float4* xsrc = (l == 0) ? (const float4*)vtok
                                      : (const float4*)(x1g + ((size_t)pload * 4 + (l - 1)) * 32);

        __syncthreads();   // previous group's slot reads complete

        // ---- K = elup1(x @ Wk) -> row
        {
            float acc[32];
#pragma unroll
            for (int j = 0; j < 32; ++j) acc[j] = 0.f;
            for (int g = 0; g < 8; ++g) {
                float4 xv = xsrc[g];
                fma4(xv, &Wk[g * 128], 32, acc);
            }
            if (act) {
                float* krow = &shr[rowbase];
#pragma unroll
                for (int j = 0; j < 32; j += 4)
                    *(float4*)&krow[j] = make_float4(elup1(acc[j]), elup1(acc[j+1]),
                                                     elup1(acc[j+2]), elup1(acc[j+3]));
            }
        }
        // ---- V = x @ Wv -> row
        {
            float acc[32];
#pragma unroll
            for (int j = 0; j < 32; ++j) acc[j] = 0.f;
            for (int g = 0; g < 8; ++g) {
                float4 xv = xsrc[g];
                fma4(xv, &Wv[g * 128], 32, acc);
            }
            if (act) {
                float* vrow = &shr[rowbase + 32];
#pragma unroll
                for (int j = 0; j < 32; j += 4)
                    *(float4*)&vrow[j] = make_float4(acc[j], acc[j+1], acc[j+2], acc[j+3]);
            }
        }
        __syncthreads();   // K/V rows visible

        // ---- attention fused with Wm: macc = attnout @ Wm
        float macc[32];
#pragma unroll
        for (int j = 0; j < 32; ++j) macc[j] = 0.f;
        for (int h = 0; h < 8; ++h) {
            // Q head h for own token (recomputed; x L1-hot, weights scalar)
            float q0 = 0.f, q1 = 0.f, q2 = 0.f, q3 = 0.f;
            for (int g = 0; g < 8; ++g) {
                float4 xv = xsrc[g];
                const float* w = &Wq[g * 128 + h * 4];
                q0 = fmaf(xv.x, w[0],  q0); q1 = fmaf(xv.x, w[1],  q1);
                q2 = fmaf(xv.x, w[2],  q2); q3 = fmaf(xv.x, w[3],  q3);
                q0 = fmaf(xv.y, w[32], q0); q1 = fmaf(xv.y, w[33], q1);
                q2 = fmaf(xv.y, w[34], q2); q3 = fmaf(xv.y, w[35], q3);
                q0 = fmaf(xv.z, w[64], q0); q1 = fmaf(xv.z, w[65], q1);
                q2 = fmaf(xv.z, w[66], q2); q3 = fmaf(xv.z, w[67], q3);
                q0 = fmaf(xv.w, w[96], q0); q1 = fmaf(xv.w, w[97], q1);
                q2 = fmaf(xv.w, w[98], q2); q3 = fmaf(xv.w, w[99], q3);
            }
            q0 = elup1(q0); q1 = elup1(q1); q2 = elup1(q2); q3 = elup1(q3);

            float kvm[16] = {0,0,0,0,0,0,0,0,0,0,0,0,0,0,0,0};
            float ks0 = 0.f, ks1 = 0.f, ks2 = 0.f, ks3 = 0.f;
#pragma unroll
            for (int l2 = 0; l2 < 5; ++l2) {
                const float* row = &shr[(pl * 5 + l2) * 68 + h * 4];
                float4 K4 = *(const float4*)row;
                float4 V4 = *(const float4*)(row + 32);
                kvm[0]  = fmaf(K4.x, V4.x, kvm[0]);  kvm[1]  = fmaf(K4.x, V4.y, kvm[1]);
                kvm[2]  = fmaf(K4.x, V4.z, kvm[2]);  kvm[3]  = fmaf(K4.x, V4.w, kvm[3]);
                kvm[4]  = fmaf(K4.y, V4.x, kvm[4]);  kvm[5]  = fmaf(K4.y, V4.y, kvm[5]);
                kvm[6]  = fmaf(K4.y, V4.z, kvm[6]);  kvm[7]  = fmaf(K4.y, V4.w, kvm[7]);
                kvm[8]  = fmaf(K4.z, V4.x, kvm[8]);  kvm[9]  = fmaf(K4.z, V4.y, kvm[9]);
                kvm[10] = fmaf(K4.z, V4.z, kvm[10]); kvm[11] = fmaf(K4.z, V4.w, kvm[11]);
                kvm[12] = fmaf(K4.w, V4.x, kvm[12]); kvm[13] = fmaf(K4.w, V4.y, kvm[13]);
                kvm[14] = fmaf(K4.w, V4.z, kvm[14]); kvm[15] = fmaf(K4.w, V4.w, kvm[15]);
                ks0 += K4.x; ks1 += K4.y; ks2 += K4.z; ks3 += K4.w;
            }
            float den = 1e-6f + q0*ks0 + q1*ks1 + q2*ks2 + q3*ks3;
            float inv = 1.f / den;
            float o0 = (q0*kvm[0] + q1*kvm[4] + q2*kvm[8]  + q3*kvm[12]) * inv;
            float o1 = (q0*kvm[1] + q1*kvm[5] + q2*kvm[9]  + q3*kvm[13]) * inv;
            float o2 = (q0*kvm[2] + q1*kvm[6] + q2*kvm[10] + q3*kvm[14]) * inv;
            float o3 = (q0*kvm[3] + q1*kvm[7] + q2*kvm[11] + q3*kvm[15]) * inv;

            const float* wm = &Wm[h * 4 * 32];
#pragma unroll
            for (int j = 0; j < 32; ++j) macc[j] = fmaf(o0, wm[j],      macc[j]);
#pragma unroll
            for (int j = 0; j < 32; ++j) macc[j] = fmaf(o1, wm[32 + j], macc[j]);
#pragma unroll
            for (int j = 0; j < 32; ++j) macc[j] = fmaf(o2, wm[64 + j], macc[j]);
#pragma unroll
            for (int j = 0; j < 32; ++j) macc[j] = fmaf(o3, wm[96 + j], macc[j]);
        }

        // ---- LN1 -> msg (registers)
        float msg[32];
        {
            float s1 = 0.f, s2 = 0.f;
#pragma unroll
            for (int j = 0; j < 32; ++j) { s1 += macc[j]; s2 += macc[j] * macc[j]; }
            float m  = s1 * (1.f / 32.f);
            float va = s2 * (1.f / 32.f) - m * m;
            float rs = rsqrtf(va + 1e-5f);
#pragma unroll
            for (int j = 0; j < 32; ++j)
                msg[j] = (macc[j] - m) * rs * g1v[j] + b1v[j];
        }
        __syncthreads();   // all K/V reads done; shr becomes slot scratch

        // ---- stage msg to slots [0,4096)
#pragma unroll
        for (int g = 0; g < 8; ++g)
            *(float4*)&shr[(g * K2_BLK + t) * 4] =
                make_float4(msg[4*g], msg[4*g+1], msg[4*g+2], msg[4*g+3]);

        // ---- FFN: two 32-col halves; h slots at [4096,8192)
        float oacc[32];
#pragma unroll
        for (int j = 0; j < 32; ++j) oacc[j] = 0.f;
        for (int half = 0; half < 2; ++half) {
            const int j0 = half * 32;
            float hacc[32];
#pragma unroll
            for (int j = 0; j < 32; ++j) hacc[j] = 0.f;
            for (int g = 0; g < 8; ++g) {                 // x part (rows 0..31)
                float4 xv = xsrc[g];
                fma4(xv, &W1[(g * 4) * 64 + j0], 64, hacc);
            }
            for (int g = 0; g < 8; ++g) {                 // msg part (rows 32..63)
                float4 mv = *(const float4*)&shr[(g * K2_BLK + t) * 4];
                fma4(mv, &W1[(32 + g * 4) * 64 + j0], 64, hacc);
            }
#pragma unroll
            for (int j = 0; j < 32; j += 4)
                *(float4*)&shr[4096 + ((j >> 2) * K2_BLK + t) * 4] =
                    make_float4(fmaxf(hacc[j], 0.f),   fmaxf(hacc[j+1], 0.f),
                                fmaxf(hacc[j+2], 0.f), fmaxf(hacc[j+3], 0.f));
            for (int g = 0; g < 8; ++g) {                 // W2 rows j0..j0+31
                float4 hv = *(const float4*)&shr[4096 + (g * K2_BLK + t) * 4];
                fma4(hv, &W2[(j0 + g * 4) * 32], 32, oacc);
            }
        }

        // ---- LN2, residual, store
        {
            float s1 = 0.f, s2 = 0.f;
#pragma unroll
            for (int j = 0; j < 32; ++j) { s1 += oacc[j]; s2 += oacc[j] * oacc[j]; }
            float m  = s1 * (1.f / 32.f);
            float va = s2 * (1.f / 32.f) - m * m;
            float rs = rsqrtf(va + 1e-5f);

            if (valid) {
                float y[32];
#pragma unroll
                for (int g = 0; g < 8; ++g) {
                    float4 x4 = xsrc[g];
                    y[4*g] = x4.x; y[4*g+1] = x4.y; y[4*g+2] = x4.z; y[4*g+3] = x4.w;
                }
#pragma unroll
                for (int j = 0; j < 32; ++j)
                    y[j] += (oacc[j] - m) * rs * g2v[j] + b2v[j];

                if (l == 0) {
                    float4* dst = (float4*)(xr + (size_t)p * 40);
#pragma unroll
                    for (int g = 0; g < 8; ++g)
                        dst[g] = make_float4(y[4*g], y[4*g+1], y[4*g+2], y[4*g+3]);
                    int sidx = p & 127;
#pragma unroll
                    for (int c = 0; c < 8; ++c) {
                        float den = (c < 2) ? 1.f : (c < 4) ? 10.f : (c < 6) ? 100.f : 1000.f;
                        float arg = (float)sidx / den;
                        xr[(size_t)p * 40 + 32 + c] = (c & 1) ? cosf(arg) : sinf(arg);
                    }
                } else {
                    float4* dst = (float4*)(x1g + ((size_t)p * 4 + (l - 1)) * 32);
#pragma unroll
                    for (int g = 0; g < 8; ++g)
                        dst[g] = make_float4(y[4*g], y[4*g+1], y[4*g+2], y[4*g+3]);
                }
            }
        }
    }
}

// ---------------------------------------------------------------------------
// K3a: layer-2 attention half (unchanged)
// ---------------------------------------------------------------------------
__global__ __launch_bounds__(320) void k3a_attn(
    const float* __restrict__ xr,
    const float* __restrict__ Wq, const float* __restrict__ Wk,
    const float* __restrict__ Wv, const float* __restrict__ Wm,
    const float* __restrict__ g1, const float* __restrict__ b1,
    float* __restrict__ msg)
{
    __shared__ float kb[5120];
    __shared__ float vb[5120];
    __shared__ float wb[1600];
    __shared__ float kvb[200];
    __shared__ float ksb[40];
    int t = threadIdx.x, r = blockIdx.x;
    const float* xbase = xr + (size_t)r * 5120;
    int lg = t / 40, c = t % 40;

    for (int i = t; i < 1600; i += 320) wb[i] = Wk[i];
    __syncthreads();
    {
        float acc[16];
#pragma unroll
        for (int i = 0; i < 16; ++i) acc[i] = 0.f;
        for (int kk = 0; kk < 40; ++kk) {
            float w = wb[kk * 40 + c];
#pragma unroll
            for (int i = 0; i < 16; ++i) acc[i] += xbase[(lg * 16 + i) * 40 + kk] * w;
        }
#pragma unroll
        for (int i = 0; i < 16; ++i) kb[(lg * 16 + i) * 40 + c] = elup1(acc[i]);
    }
    __syncthreads();
    for (int i = t; i < 1600; i += 320) wb[i] = Wv[i];
    __syncthreads();
    {
        float acc[16];
#pragma unroll
        for (int i = 0; i < 16; ++i) acc[i] = 0.f;
        for (int kk = 0; kk < 40; ++kk) {
            float w = wb[kk * 40 + c];
#pragma unroll
            for (int i = 0; i < 16; ++i) acc[i] += xbase[(lg * 16 + i) * 40 + kk] * w;
        }
#pragma unroll
        for (int i = 0; i < 16; ++i) vb[(lg * 16 + i) * 40 + c] = acc[i];
    }
    __syncthreads();
    if (t < 200) {
        int h = t / 25, e = (t / 5) % 5, d = t % 5;
        float kv = 0.f, ks = 0.f;
        for (int s2 = 0; s2 < 128; ++s2) {
            float kvv = kb[s2 * 40 + h * 5 + e];
            float vv  = vb[s2 * 40 + h * 5 + d];
            kv += kvv * vv; ks += kvv;
        }
        kvb[t] = kv;
        if (d == 0) ksb[h * 5 + e] = ks;
    }
    __syncthreads();
    for (int i = t; i < 1600; i += 320) wb[i] = Wq[i];
    __syncthreads();
    {
        float acc[16];
#pragma unroll
        for (int i = 0; i < 16; ++i) acc[i] = 0.f;
        for (int kk = 0; kk < 40; ++kk) {
            float w = wb[kk * 40 + c];
#pragma unroll
            for (int i = 0; i < 16; ++i) acc[i] += xbase[(lg * 16 + i) * 40 + kk] * w;
        }
#pragma unroll
        for (int i = 0; i < 16; ++i) kb[(lg * 16 + i) * 40 + c] = elup1(acc[i]);
    }
    __syncthreads();
    {
        int h = c / 5, d = c % 5;
#pragma unroll 4
        for (int i = 0; i < 16; ++i) {
            int l = lg * 16 + i;
            float den = 1e-6f, o = 0.f;
#pragma unroll
            for (int e = 0; e < 5; ++e) {
                float q = kb[l * 40 + h * 5 + e];
                den += q * ksb[h * 5 + e];
                o   += q * kvb[h * 25 + e * 5 + d];
            }
            vb[l * 40 + c] = o / den;
        }
    }
    __syncthreads();
    for (int i = t; i < 1600; i += 320) wb[i] = Wm[i];
    __syncthreads();
    {
        float acc[16];
#pragma unroll
        for (int i = 0; i < 16; ++i) acc[i] = 0.f;
        for (int kk = 0; kk < 40; ++kk) {
            float w = wb[kk * 40 + c];
#pragma unroll
            for (int i = 0; i < 16; ++i) acc[i] += vb[(lg * 16 + i) * 40 + kk] * w;
        }
#pragma unroll
        for (int i = 0; i < 16; ++i) kb[(lg * 16 + i) * 40 + c] = acc[i];
    }
    __syncthreads();
    if (t < 128) {
        float s1 = 0.f, s2v = 0.f;
        for (int j = 0; j < 40; ++j) { float x = kb[t * 40 + j]; s1 += x; s2v += x * x; }
        float m = s1 * (1.f / 40.f), va = s2v * (1.f / 40.f) - m * m;
        float rs = rsqrtf(va + 1e-5f);
        for (int j = 0; j < 40; ++j)
            msg[((size_t)r * 128 + t) * 40 + j] = (kb[t * 40 + j] - m) * rs * g1[j] + b1[j];
    }
}

// ---------------------------------------------------------------------------
// K3b: layer-2 FFN half (unchanged)
// ---------------------------------------------------------------------------
__global__ __launch_bounds__(320) void k3b_ffn(
    float* __restrict__ xr, const float* __restrict__ msg,
    const float* __restrict__ W1, const float* __restrict__ W2,
    const float* __restrict__ g2, const float* __restrict__ b2)
{
    __shared__ float hb[10240];
    __shared__ float wb[3200];
    int t = threadIdx.x, r = blockIdx.x;
    int lg = t / 40, c = t % 40;
    const float* xbase = xr + (size_t)r * 5120;
    const float* mbase = msg + (size_t)r * 5120;

    float hA[16], hB[16];
#pragma unroll
    for (int i = 0; i < 16; ++i) { hA[i] = 0.f; hB[i] = 0.f; }

    for (int i = t; i < 3200; i += 320) wb[i] = W1[i];
    __syncthreads();
    for (int kk = 0; kk < 40; ++kk) {
        float wa = wb[kk * 80 + c], wbb = wb[kk * 80 + c + 40];
#pragma unroll
        for (int i = 0; i < 16; ++i) {
            float xv = xbase[(lg * 16 + i) * 40 + kk];
            hA[i] += xv * wa; hB[i] += xv * wbb;
        }
    }
    __syncthreads();
    for (int i = t; i < 3200; i += 320) wb[i] = W1[3200 + i];
    __syncthreads();
    for (int kk = 0; kk < 40; ++kk) {
        float wa = wb[kk * 80 + c], wbb = wb[kk * 80 + c + 40];
#pragma unroll
        for (int i = 0; i < 16; ++i) {
            float mv = mbase[(lg * 16 + i) * 40 + kk];
            hA[i] += mv * wa; hB[i] += mv * wbb;
        }
    }
#pragma unroll
    for (int i = 0; i < 16; ++i) {
        hb[(lg * 16 + i) * 80 + c]      = fmaxf(hA[i], 0.f);
        hb[(lg * 16 + i) * 80 + c + 40] = fmaxf(hB[i], 0.f);
    }
    __syncthreads();
    for (int i = t; i < 3200; i += 320) wb[i] = W2[i];
    __syncthreads();
    float oa[16];
#pragma unroll
    for (int i = 0; i < 16; ++i) oa[i] = 0.f;
    for (int kk = 0; kk < 80; ++kk) {
        float w = wb[kk * 40 + c];
#pragma unroll
        for (int i = 0; i < 16; ++i) oa[i] += hb[(lg * 16 + i) * 80 + kk] * w;
    }
    __syncthreads();
#pragma unroll
    for (int i = 0; i < 16; ++i) hb[(lg * 16 + i) * 40 + c] = oa[i];
    __syncthreads();
    if (t < 128) {
        float s1 = 0.f, s2v = 0.f;
        for (int j = 0; j < 40; ++j) { float x = hb[t * 40 + j]; s1 += x; s2v += x * x; }
        float m = s1 * (1.f / 40.f), va = s2v * (1.f / 40.f) - m * m;
        float rs = rsqrtf(va + 1e-5f);
        for (int j = 0; j < 40; ++j) {
            float y = xbase[t * 40 + j] + (hb[t * 40 + j] - m) * rs * g2[j] + b2[j];
            xr[(size_t)r * 5120 + t * 40 + j] = y;
        }
    }
}

// ---------------------------------------------------------------------------
// K4: srdf head (unchanged)
// ---------------------------------------------------------------------------
__global__ __launch_bounds__(256) void k4_dm(
    const float* __restrict__ xr,
    const float* __restrict__ W1, const float* __restrict__ b1,
    const float* __restrict__ W2, const float* __restrict__ b2,
    const float* __restrict__ W3, const float* __restrict__ b3,
    float* __restrict__ out1)
{
    __shared__ float s[1857];
    int t = threadIdx.x;
    for (int i = t; i < 1280; i += 256) s[i] = W1[i];
    if (t < 32) s[1280 + t] = b1[t];
    for (int i = t; i < 512; i += 256) s[1312 + i] = W2[i];
    if (t < 16) { s[1824 + t] = b2[t]; s[1840 + t] = W3[t]; }
    if (t == 0) s[1856] = b3[0];
    __syncthreads();

    int p = blockIdx.x * 256 + t;
    float x[40];
    const float4* xp = (const float4*)(xr + (size_t)p * 40);
#pragma unroll
    for (int i = 0; i < 10; ++i) {
        float4 v4 = xp[i];
        x[4*i] = v4.x; x[4*i+1] = v4.y; x[4*i+2] = v4.z; x[4*i+3] = v4.w;
    }
    float h1[32];
#pragma unroll
    for (int j = 0; j < 32; ++j) h1[j] = s[1280 + j];
    for (int k = 0; k < 40; ++k) {
        float xv = x[k];
#pragma unroll
        for (int j = 0; j < 32; ++j) h1[j] += xv * s[k * 32 + j];
    }
#pragma unroll
    for (int j = 0; j < 32; ++j) h1[j] = fmaxf(h1[j], 0.f);
    float h2[16];
#pragma unroll
    for (int j = 0; j < 16; ++j) h2[j] = s[1824 + j];
    for (int k = 0; k < 32; ++k) {
        float hv = h1[k];
#pragma unroll
        for (int j = 0; j < 16; ++j) h2[j] += hv * s[1312 + k * 16 + j];
    }
    float o = s[1856];
#pragma unroll
    for (int j = 0; j < 16; ++j) o += fmaxf(h2[j], 0.f) * s[1840 + j];
    out1[p] = o;
}

// ---------------------------------------------------------------------------
// K5: rw head + masked softmax + radiance blend (unchanged)
// ---------------------------------------------------------------------------
__global__ __launch_bounds__(256) void k5_rw(
    const float* __restrict__ vf, const float* __restrict__ dirw,
    const float* __restrict__ maskw, const float* __restrict__ rgbw,
    const float* __restrict__ W1, const float* __restrict__ b1,
    const float* __restrict__ W2, const float* __restrict__ b2,
    const float* __restrict__ W3, const float* __restrict__ b3,
    float* __restrict__ out0)
{
    __shared__ float s[721];
    int t = threadIdx.x;
    for (int i = t; i < 560; i += 256) s[i] = W1[i];
    if (t < 16) s[560 + t] = b1[t];
    if (t < 128) s[576 + t] = W2[t];
    if (t < 8) { s[704 + t] = b2[t]; s[712 + t] = W3[t]; }
    if (t == 0) s[720] = b3[0];
    __syncthreads();

    int p = blockIdx.x * 256 + t;
    float xw[4];
#pragma unroll
    for (int v = 0; v < 4; ++v) {
        float in[35];
        const float4* vp = (const float4*)(vf + ((size_t)p * 4 + v) * 32);
#pragma unroll
        for (int q = 0; q < 8; ++q) {
            float4 f4 = vp[q];
            in[4*q] = f4.x; in[4*q+1] = f4.y; in[4*q+2] = f4.z; in[4*q+3] = f4.w;
        }
        in[32] = dirw[(size_t)p * 12 + v * 3 + 0];
        in[33] = dirw[(size_t)p * 12 + v * 3 + 1];
        in[34] = dirw[(size_t)p * 12 + v * 3 + 2];
        float h1[16];
#pragma unroll
        for (int j = 0; j < 16; ++j) h1[j] = s[560 + j];
        for (int k = 0; k < 35; ++k) {
            float xv = in[k];
#pragma unroll
            for (int j = 0; j < 16; ++j) h1[j] += xv * s[k * 16 + j];
        }
        float h2[8];
#pragma unroll
        for (int j = 0; j < 8; ++j) h2[j] = s[704 + j];
        for (int k = 0; k < 16; ++k) {
            float hv = fmaxf(h1[k], 0.f);
#pragma unroll
            for (int j = 0; j < 8; ++j) h2[j] += hv * s[576 + k * 8 + j];
        }
        float o = s[720];
#pragma unroll
        for (int j = 0; j < 8; ++j) o += fmaxf(h2[j], 0.f) * s[712 + j];
        xw[v] = (maskw[(size_t)p * 4 + v] == 0.f) ? -1e9f : o;
    }
    float m = fmaxf(fmaxf(xw[0], xw[1]), fmaxf(xw[2], xw[3]));
    float e0 = expf(xw[0] - m), e1 = expf(xw[1] - m), e2 = expf(xw[2] - m), e3 = expf(xw[3] - m);
    float inv = 1.f / (e0 + e1 + e2 + e3);
    float w4[4] = { e0 * inv, e1 * inv, e2 * inv, e3 * inv };
    float r0 = 0.f, r1 = 0.f, r2 = 0.f;
#pragma unroll
    for (int v = 0; v < 4; ++v) {
        r0 += rgbw[(size_t)p * 12 + v * 3 + 0] * w4[v];
        r1 += rgbw[(size_t)p * 12 + v * 3 + 1] * w4[v];
        r2 += rgbw[(size_t)p * 12 + v * 3 + 2] * w4[v];
    }
    out0[(size_t)p * 3 + 0] = r0;
    out0[(size_t)p * 3 + 1] = r1;
    out0[(size_t)p * 3 + 2] = r2;
}

// ---------------------------------------------------------------------------
extern "C" void kernel_launch(void* const* d_in, const int* in_sizes, int n_in,
                              void* d_out, int out_size, void* d_ws, size_t ws_size,
                              hipStream_t stream) {
    (void)in_sizes; (void)n_in; (void)out_size; (void)ws_size;
    const float* p3d   = (const float*)d_in[0];
    const float* imgs  = (const float*)d_in[1];
    const float* feat  = (const float*)d_in[2];
    const float* rpi   = (const float*)d_in[3];
    const float* spi   = (const float*)d_in[4];
    const float* sp    = (const float*)d_in[5];
    const float* vtok  = (const float*)d_in[6];
    const float* vtWq  = (const float*)d_in[7];
    const float* vtWk  = (const float*)d_in[8];
    const float* vtWv  = (const float*)d_in[9];
    const float* vtWm  = (const float*)d_in[10];
    const float* vtg1  = (const float*)d_in[11];
    const float* vtb1  = (const float*)d_in[12];
    const float* vtW1  = (const float*)d_in[13];
    const float* vtW2  = (const float*)d_in[14];
    const float* vtg2  = (const float*)d_in[15];
    const float* vtb2  = (const float*)d_in[16];
    const float* rtWq  = (const float*)d_in[17];
    const float* rtWk  = (const float*)d_in[18];
    const float* rtWv  = (const float*)d_in[19];
    const float* rtWm  = (const float*)d_in[20];
    const float* rtg1  = (const float*)d_in[21];
    const float* rtb1  = (const float*)d_in[22];
    const float* rtW1  = (const float*)d_in[23];
    const float* rtW2  = (const float*)d_in[24];
    const float* rtg2  = (const float*)d_in[25];
    const float* rtb2  = (const float*)d_in[26];
    const float* dmW1  = (const float*)d_in[27];
    const float* dmb1  = (const float*)d_in[28];
    const float* dmW2  = (const float*)d_in[29];
    const float* dmb2  = (const float*)d_in[30];
    const float* dmW3  = (const float*)d_in[31];
    const float* dmb3  = (const float*)d_in[32];
    const float* rwW1  = (const float*)d_in[33];
    const float* rwb1  = (const float*)d_in[34];
    const float* rwW2  = (const float*)d_in[35];
    const float* rwb2  = (const float*)d_in[36];
    const float* rwW3  = (const float*)d_in[37];
    const float* rwb3  = (const float*)d_in[38];

    float* out  = (float*)d_out;
    float* out0 = out;
    float* out1 = out + 393216;
    float* out2 = out + 524288;

    float* ws    = (float*)d_ws;
    float* featT = ws + WS_FEATT;
    float* imgT  = ws + WS_IMGT;
    float* x1    = ws + WS_X1;
    float* xr    = ws + WS_XR;
    float* msg   = ws + WS_MSG;
    float* rgbw  = ws + WS_RGB;
    float* dirw  = ws + WS_DIR;
    float* maskw = ws + WS_MASK;

    k0_transpose<<<dim3(1024), dim3(256), 0, stream>>>(feat, imgs, featT, imgT);
    k1_geom_sample<<<dim3(2048), dim3(256), 0, stream>>>(p3d, rpi, spi, sp, featT, imgT,
                                                         x1, rgbw, dirw, maskw, out2);
    k2_loftr1<<<dim3(K2_GRID), dim3(K2_BLK), 0, stream>>>(x1, vtok, vtWq, vtWk, vtWv, vtWm,
                                                    vtg1, vtb1, vtW1, vtW2, vtg2, vtb2, xr);
    k3a_attn<<<dim3(1024), dim3(320), 0, stream>>>(xr, rtWq, rtWk, rtWv, rtWm, rtg1, rtb1, msg);
    k3b_ffn<<<dim3(1024), dim3(320), 0, stream>>>(xr, msg, rtW1, rtW2, rtg2, rtb2);
    k4_dm<<<dim3(512), dim3(256), 0, stream>>>(xr, dmW1, dmb1, dmW2, dmb2, dmW3, dmb3, out1);
    k5_rw<<<dim3(512), dim3(256), 0, stream>>>(x1, dirw, maskw, rgbw,
                                               rwW1, rwb1, rwW2, rwb2, rwW3, rwb3, out0);
}

// Round 5
// 1010.360 us; speedup vs baseline: 9.6716x; 1.1186x over previous
//
#include <hip/hip_runtime.h>
#include <math.h>

// Problem constants
#define NPTS   131072      // RN*SN = 1024*128
#define NVIEW  4
#define IMH    256
#define IMW    256

// Workspace layout (float offsets)
#define WS_FEATT   0u
#define WS_IMGT    8388608u
#define WS_X1      9437184u
#define WS_XR      26214400u
#define WS_MSG     31457280u
#define WS_RGB     36700160u
#define WS_DIR     38273024u
#define WS_MASK    39845888u

__device__ __forceinline__ float elup1(float t) { return t > 0.f ? t + 1.f : expf(t); }

// ---------------------------------------------------------------------------
// K0: (v,c,y,x) -> (v,y,x,c) transpose for feat (32ch) and rgb (3ch, padded 4)
// ---------------------------------------------------------------------------
__global__ __launch_bounds__(256) void k0_transpose(
    const float* __restrict__ feat, const float* __restrict__ img,
    float* __restrict__ featT, float* __restrict__ imgT)
{
    int tid = blockIdx.x * 256 + threadIdx.x;
    int v = tid >> 16, pix = tid & 65535;
    float buf[32];
#pragma unroll
    for (int c = 0; c < 32; ++c)
        buf[c] = feat[((size_t)(v * 32 + c) << 16) + pix];
    float4* dst = (float4*)(featT + ((size_t)tid << 5));
#pragma unroll
    for (int q = 0; q < 8; ++q)
        dst[q] = make_float4(buf[4*q], buf[4*q+1], buf[4*q+2], buf[4*q+3]);
    float4 rgb;
    rgb.x = img[((size_t)(v * 3 + 0) << 16) + pix];
    rgb.y = img[((size_t)(v * 3 + 1) << 16) + pix];
    rgb.z = img[((size_t)(v * 3 + 2) << 16) + pix];
    rgb.w = 0.f;
    *(float4*)(imgT + ((size_t)tid << 2)) = rgb;
}

// ---------------------------------------------------------------------------
// K1: per (point, view): geometry + bilinear sample (unchanged)
// ---------------------------------------------------------------------------
__global__ __launch_bounds__(256) void k1_geom_sample(
    const float* __restrict__ p3d, const float* __restrict__ rpi,
    const float* __restrict__ spi, const float* __restrict__ sp,
    const float* __restrict__ featT, const float* __restrict__ imgT,
    float* __restrict__ x1, float* __restrict__ rgbw,
    float* __restrict__ dirw, float* __restrict__ maskw,
    float* __restrict__ outpip)
{
    int tid = blockIdx.x * 256 + threadIdx.x;
    int p = tid >> 2, v = tid & 3;
    float X = p3d[p * 3 + 0], Y = p3d[p * 3 + 1], Z = p3d[p * 3 + 2];

    float a0 = X - rpi[3], a1 = Y - rpi[7], a2 = Z - rpi[11];
    float na = sqrtf(a0 * a0 + a1 * a1 + a2 * a2);
    a0 /= na; a1 /= na; a2 /= na;
    const float* sv = spi + v * 16;
    float b0 = X - sv[3], b1 = Y - sv[7], b2 = Z - sv[11];
    float nb = sqrtf(b0 * b0 + b1 * b1 + b2 * b2);
    b0 /= nb; b1 /= nb; b2 /= nb;
    dirw[(size_t)p * 12 + v * 3 + 0] = a0 - b0;
    dirw[(size_t)p * 12 + v * 3 + 1] = a1 - b1;
    dirw[(size_t)p * 12 + v * 3 + 2] = a2 - b2;

    const float* P = sp + v * 16;
    float pip0 = P[0] * X + P[1] * Y + P[2]  * Z + P[3];
    float pip1 = P[4] * X + P[5] * Y + P[6]  * Z + P[7];
    float pip2 = P[8] * X + P[9] * Y + P[10] * Z + P[11];
    outpip[(size_t)(v * 3 + 0) * NPTS + p] = pip0;
    outpip[(size_t)(v * 3 + 1) * NPTS + p] = pip1;
    outpip[(size_t)(v * 3 + 2) * NPTS + p] = pip2;

    float gx = pip0 / pip2, gy = pip1 / pip2;
    float inb = (gx >= 0.f && gx <= 255.f && gy >= 0.f && gy <= 255.f) ? 1.f : 0.f;
    float mvd = pip2 > 0.f ? 1.f : 0.f;
    maskw[(size_t)p * 4 + v] = inb * mvd;

    float x0f = floorf(gx), y0f = floorf(gy);
    float wx = gx - x0f, wy = gy - y0f;
    int ix0 = (int)x0f, iy0 = (int)y0f;
    float tw[4] = { (1.f-wx)*(1.f-wy), wx*(1.f-wy), (1.f-wx)*wy, wx*wy };
    int tdx[4] = { 0, 1, 0, 1 };
    int tdy[4] = { 0, 0, 1, 1 };

    float facc[32];
#pragma unroll
    for (int c = 0; c < 32; ++c) facc[c] = 0.f;
    float r0 = 0.f, r1 = 0.f, r2 = 0.f;

#pragma unroll
    for (int tno = 0; tno < 4; ++tno) {
        int ix = ix0 + tdx[tno], iy = iy0 + tdy[tno];
        float valid = (ix >= 0 && ix < IMW && iy >= 0 && iy < IMH) ? 1.f : 0.f;
        int cx = min(max(ix, 0), IMW - 1), cy = min(max(iy, 0), IMH - 1);
        float wgt = tw[tno] * valid;
        size_t base = ((size_t)v << 16) + ((size_t)cy << 8) + (size_t)cx;
        const float4* fp = (const float4*)(featT + base * 32);
#pragma unroll
        for (int q = 0; q < 8; ++q) {
            float4 f4 = fp[q];
            facc[4*q+0] += f4.x * wgt; facc[4*q+1] += f4.y * wgt;
            facc[4*q+2] += f4.z * wgt; facc[4*q+3] += f4.w * wgt;
        }
        float4 rp = *(const float4*)(imgT + base * 4);
        r0 += rp.x * wgt; r1 += rp.y * wgt; r2 += rp.z * wgt;
    }

    float4* xd = (float4*)(x1 + ((size_t)p * 4 + v) * 32);
#pragma unroll
    for (int q = 0; q < 8; ++q)
        xd[q] = make_float4(facc[4*q], facc[4*q+1], facc[4*q+2], facc[4*q+3]);
    rgbw[(size_t)p * 12 + v * 3 + 0] = r0;
    rgbw[(size_t)p * 12 + v * 3 + 1] = r1;
    rgbw[(size_t)p * 12 + v * 3 + 2] = r2;
}

// ---------------------------------------------------------------------------
// K2 v8 (unchanged winner): row-per-thread, weights via wave-uniform global
// reads (scalarized s_load), LDS only for K/V rows + msg/h slots.
// ---------------------------------------------------------------------------
#define K2_BLK    128
#define K2_PTS    24
#define K2_GRID   1024
#define K2_NGRP   ((NPTS + K2_PTS - 1) / K2_PTS)   // 5462

// acc[j] += xv.{x,y,z,w} * w[u*stride + j], j=0..31  (w uniform across lanes)
__device__ __forceinline__ void fma4(const float4 xv, const float* __restrict__ w,
                                     const int stride, float* __restrict__ acc)
{
#pragma unroll
    for (int j = 0; j < 32; ++j) acc[j] = fmaf(xv.x, w[j],            acc[j]);
#pragma unroll
    for (int j = 0; j < 32; ++j) acc[j] = fmaf(xv.y, w[stride + j],   acc[j]);
#pragma unroll
    for (int j = 0; j < 32; ++j) acc[j] = fmaf(xv.z, w[2*stride + j], acc[j]);
#pragma unroll
    for (int j = 0; j < 32; ++j) acc[j] = fmaf(xv.w, w[3*stride + j], acc[j]);
}

// 40-wide variant for layer-2 (D_RAY = 40)
__device__ __forceinline__ void fma40(const float4 xv, const float* __restrict__ w,
                                      const int stride, float* __restrict__ acc)
{
#pragma unroll
    for (int j = 0; j < 40; ++j) acc[j] = fmaf(xv.x, w[j],            acc[j]);
#pragma unroll
    for (int j = 0; j < 40; ++j) acc[j] = fmaf(xv.y, w[stride + j],   acc[j]);
#pragma unroll
    for (int j = 0; j < 40; ++j) acc[j] = fmaf(xv.z, w[2*stride + j], acc[j]);
#pragma unroll
    for (int j = 0; j < 40; ++j) acc[j] = fmaf(xv.w, w[3*stride + j], acc[j]);
}

__global__ __launch_bounds__(K2_BLK) void k2_loftr1(
    float* __restrict__ x1g, const float* __restrict__ vtok,
    const float* __restrict__ Wq, const float* __restrict__ Wk,
    const float* __restrict__ Wv, const float* __restrict__ Wm,
    const float* __restrict__ g1v, const float* __restrict__ b1v,
    const float* __restrict__ W1, const float* __restrict__ W2,
    const float* __restrict__ g2v, const float* __restrict__ b2v,
    float* __restrict__ xr)
{
    __shared__ float shr[8192];    // K/V rows | msg+h slots   (32 KB)

    int t = threadIdx.x;
    int pl = t / 5, l = t - pl * 5;
    bool act = (t < K2_PTS * 5);
    if (!act) { pl = 0; l = 0; }
    const int rowbase = (pl * 5 + l) * 68;

    for (int grp = blockIdx.x; grp < K2_NGRP; grp += gridDim.x) {
        int p = grp * K2_PTS + pl;
        bool valid = act && (p < NPTS);
        int pload = p < NPTS ? p : NPTS - 1;
        const float4* xsrc = (l == 0) ? (const float4*)vtok
                                      : (const float4*)(x1g + ((size_t)pload * 4 + (l - 1)) * 32);

        __syncthreads();   // previous group's slot reads complete

        // ---- K = elup1(x @ Wk) -> row
        {
            float acc[32];
#pragma unroll
            for (int j = 0; j < 32; ++j) acc[j] = 0.f;
            for (int g = 0; g < 8; ++g) {
                float4 xv = xsrc[g];
                fma4(xv, &Wk[g * 128], 32, acc);
            }
            if (act) {
                float* krow = &shr[rowbase];
#pragma unroll
                for (int j = 0; j < 32; j += 4)
                    *(float4*)&krow[j] = make_float4(elup1(acc[j]), elup1(acc[j+1]),
                                                     elup1(acc[j+2]), elup1(acc[j+3]));
            }
        }
        // ---- V = x @ Wv -> row
        {
            float acc[32];
#pragma unroll
            for (int j = 0; j < 32; ++j) acc[j] = 0.f;
            for (int g = 0; g < 8; ++g) {
                float4 xv = xsrc[g];
                fma4(xv, &Wv[g * 128], 32, acc);
            }
            if (act) {
                float* vrow = &shr[rowbase + 32];
#pragma unroll
                for (int j = 0; j < 32; j += 4)
                    *(float4*)&vrow[j] = make_float4(acc[j], acc[j+1], acc[j+2], acc[j+3]);
            }
        }
        __syncthreads();   // K/V rows visible

        // ---- attention fused with Wm: macc = attnout @ Wm
        float macc[32];
#pragma unroll
        for (int j = 0; j < 32; ++j) macc[j] = 0.f;
        for (int h = 0; h < 8; ++h) {
            float q0 = 0.f, q1 = 0.f, q2 = 0.f, q3 = 0.f;
            for (int g = 0; g < 8; ++g) {
                float4 xv = xsrc[g];
                const float* w = &Wq[g * 128 + h * 4];
                q0 = fmaf(xv.x, w[0],  q0); q1 = fmaf(xv.x, w[1],  q1);
                q2 = fmaf(xv.x, w[2],  q2); q3 = fmaf(xv.x, w[3],  q3);
                q0 = fmaf(xv.y, w[32], q0); q1 = fmaf(xv.y, w[33], q1);
                q2 = fmaf(xv.y, w[34], q2); q3 = fmaf(xv.y, w[35], q3);
                q0 = fmaf(xv.z, w[64], q0); q1 = fmaf(xv.z, w[65], q1);
                q2 = fmaf(xv.z, w[66], q2); q3 = fmaf(xv.z, w[67], q3);
                q0 = fmaf(xv.w, w[96], q0); q1 = fmaf(xv.w, w[97], q1);
                q2 = fmaf(xv.w, w[98], q2); q3 = fmaf(xv.w, w[99], q3);
            }
            q0 = elup1(q0); q1 = elup1(q1); q2 = elup1(q2); q3 = elup1(q3);

            float kvm[16] = {0,0,0,0,0,0,0,0,0,0,0,0,0,0,0,0};
            float ks0 = 0.f, ks1 = 0.f, ks2 = 0.f, ks3 = 0.f;
#pragma unroll
            for (int l2 = 0; l2 < 5; ++l2) {
                const float* row = &shr[(pl * 5 + l2) * 68 + h * 4];
                float4 K4 = *(const float4*)row;
                float4 V4 = *(const float4*)(row + 32);
                kvm[0]  = fmaf(K4.x, V4.x, kvm[0]);  kvm[1]  = fmaf(K4.x, V4.y, kvm[1]);
                kvm[2]  = fmaf(K4.x, V4.z, kvm[2]);  kvm[3]  = fmaf(K4.x, V4.w, kvm[3]);
                kvm[4]  = fmaf(K4.y, V4.x, kvm[4]);  kvm[5]  = fmaf(K4.y, V4.y, kvm[5]);
                kvm[6]  = fmaf(K4.y, V4.z, kvm[6]);  kvm[7]  = fmaf(K4.y, V4.w, kvm[7]);
                kvm[8]  = fmaf(K4.z, V4.x, kvm[8]);  kvm[9]  = fmaf(K4.z, V4.y, kvm[9]);
                kvm[10] = fmaf(K4.z, V4.z, kvm[10]); kvm[11] = fmaf(K4.z, V4.w, kvm[11]);
                kvm[12] = fmaf(K4.w, V4.x, kvm[12]); kvm[13] = fmaf(K4.w, V4.y, kvm[13]);
                kvm[14] = fmaf(K4.w, V4.z, kvm[14]); kvm[15] = fmaf(K4.w, V4.w, kvm[15]);
                ks0 += K4.x; ks1 += K4.y; ks2 += K4.z; ks3 += K4.w;
            }
            float den = 1e-6f + q0*ks0 + q1*ks1 + q2*ks2 + q3*ks3;
            float inv = 1.f / den;
            float o0 = (q0*kvm[0] + q1*kvm[4] + q2*kvm[8]  + q3*kvm[12]) * inv;
            float o1 = (q0*kvm[1] + q1*kvm[5] + q2*kvm[9]  + q3*kvm[13]) * inv;
            float o2 = (q0*kvm[2] + q1*kvm[6] + q2*kvm[10] + q3*kvm[14]) * inv;
            float o3 = (q0*kvm[3] + q1*kvm[7] + q2*kvm[11] + q3*kvm[15]) * inv;

            const float* wm = &Wm[h * 4 * 32];
#pragma unroll
            for (int j = 0; j < 32; ++j) macc[j] = fmaf(o0, wm[j],      macc[j]);
#pragma unroll
            for (int j = 0; j < 32; ++j) macc[j] = fmaf(o1, wm[32 + j], macc[j]);
#pragma unroll
            for (int j = 0; j < 32; ++j) macc[j] = fmaf(o2, wm[64 + j], macc[j]);
#pragma unroll
            for (int j = 0; j < 32; ++j) macc[j] = fmaf(o3, wm[96 + j], macc[j]);
        }

        // ---- LN1 -> msg (registers)
        float msg[32];
        {
            float s1 = 0.f, s2 = 0.f;
#pragma unroll
            for (int j = 0; j < 32; ++j) { s1 += macc[j]; s2 += macc[j] * macc[j]; }
            float m  = s1 * (1.f / 32.f);
            float va = s2 * (1.f / 32.f) - m * m;
            float rs = rsqrtf(va + 1e-5f);
#pragma unroll
            for (int j = 0; j < 32; ++j)
                msg[j] = (macc[j] - m) * rs * g1v[j] + b1v[j];
        }
        __syncthreads();   // all K/V reads done; shr becomes slot scratch

        // ---- stage msg to slots [0,4096)
#pragma unroll
        for (int g = 0; g < 8; ++g)
            *(float4*)&shr[(g * K2_BLK + t) * 4] =
                make_float4(msg[4*g], msg[4*g+1], msg[4*g+2], msg[4*g+3]);

        // ---- FFN: two 32-col halves; h slots at [4096,8192)
        float oacc[32];
#pragma unroll
        for (int j = 0; j < 32; ++j) oacc[j] = 0.f;
        for (int half = 0; half < 2; ++half) {
            const int j0 = half * 32;
            float hacc[32];
#pragma unroll
            for (int j = 0; j < 32; ++j) hacc[j] = 0.f;
            for (int g = 0; g < 8; ++g) {                 // x part (rows 0..31)
                float4 xv = xsrc[g];
                fma4(xv, &W1[(g * 4) * 64 + j0], 64, hacc);
            }
            for (int g = 0; g < 8; ++g) {                 // msg part (rows 32..63)
                float4 mv = *(const float4*)&shr[(g * K2_BLK + t) * 4];
                fma4(mv, &W1[(32 + g * 4) * 64 + j0], 64, hacc);
            }
#pragma unroll
            for (int j = 0; j < 32; j += 4)
                *(float4*)&shr[4096 + ((j >> 2) * K2_BLK + t) * 4] =
                    make_float4(fmaxf(hacc[j], 0.f),   fmaxf(hacc[j+1], 0.f),
                                fmaxf(hacc[j+2], 0.f), fmaxf(hacc[j+3], 0.f));
            for (int g = 0; g < 8; ++g) {                 // W2 rows j0..j0+31
                float4 hv = *(const float4*)&shr[4096 + (g * K2_BLK + t) * 4];
                fma4(hv, &W2[(j0 + g * 4) * 32], 32, oacc);
            }
        }

        // ---- LN2, residual, store
        {
            float s1 = 0.f, s2 = 0.f;
#pragma unroll
            for (int j = 0; j < 32; ++j) { s1 += oacc[j]; s2 += oacc[j] * oacc[j]; }
            float m  = s1 * (1.f / 32.f);
            float va = s2 * (1.f / 32.f) - m * m;
            float rs = rsqrtf(va + 1e-5f);

            if (valid) {
                float y[32];
#pragma unroll
                for (int g = 0; g < 8; ++g) {
                    float4 x4 = xsrc[g];
                    y[4*g] = x4.x; y[4*g+1] = x4.y; y[4*g+2] = x4.z; y[4*g+3] = x4.w;
                }
#pragma unroll
                for (int j = 0; j < 32; ++j)
                    y[j] += (oacc[j] - m) * rs * g2v[j] + b2v[j];

                if (l == 0) {
                    float4* dst = (float4*)(xr + (size_t)p * 40);
#pragma unroll
                    for (int g = 0; g < 8; ++g)
                        dst[g] = make_float4(y[4*g], y[4*g+1], y[4*g+2], y[4*g+3]);
                    int sidx = p & 127;
#pragma unroll
                    for (int c = 0; c < 8; ++c) {
                        float den = (c < 2) ? 1.f : (c < 4) ? 10.f : (c < 6) ? 100.f : 1000.f;
                        float arg = (float)sidx / den;
                        xr[(size_t)p * 40 + 32 + c] = (c & 1) ? cosf(arg) : sinf(arg);
                    }
                } else {
                    float4* dst = (float4*)(x1g + ((size_t)p * 4 + (l - 1)) * 32);
#pragma unroll
                    for (int g = 0; g < 8; ++g)
                        dst[g] = make_float4(y[4*g], y[4*g+1], y[4*g+2], y[4*g+3]);
                }
            }
        }
    }
}

// ---------------------------------------------------------------------------
// K3a v2: layer-2 attention, token-per-thread (k2-v8 template).
// 128 thr/block = 1 row of 128 tokens; weights via wave-uniform global reads
// (scalarize to s_load); x re-read from global per phase (L1-hot).
// LDS only for transposed K/V (stride 132: idx*132%32 spreads 8 bank groups
// for the kv-reduce's per-lane b128 reads) + kvb/ksb. 43.2 KB -> 3 blk/CU.
// Old version: ~1:1 load:FMA on broadcast xbase reads + 10 barriers.
// ---------------------------------------------------------------------------
#define KT_STRIDE 132
__global__ __launch_bounds__(128) void k3a_attn(
    const float* __restrict__ xr,
    const float* __restrict__ Wq, const float* __restrict__ Wk,
    const float* __restrict__ Wv, const float* __restrict__ Wm,
    const float* __restrict__ g1, const float* __restrict__ b1,
    float* __restrict__ msg)
{
    __shared__ float KT[40 * KT_STRIDE];
    __shared__ float VT[40 * KT_STRIDE];
    __shared__ float kvb[200];
    __shared__ float ksb[40];

    int t = threadIdx.x, r = blockIdx.x;
    const float4* x4 = (const float4*)(xr + ((size_t)r * 128 + t) * 40);

    // ---- K = elup1(x @ Wk) -> KT columns; V = x @ Wv -> VT columns
    {
        float acc[40];
#pragma unroll
        for (int j = 0; j < 40; ++j) acc[j] = 0.f;
        for (int g = 0; g < 10; ++g)
            fma40(x4[g], &Wk[g * 160], 40, acc);
#pragma unroll
        for (int j = 0; j < 40; ++j) KT[j * KT_STRIDE + t] = elup1(acc[j]);
    }
    {
        float acc[40];
#pragma unroll
        for (int j = 0; j < 40; ++j) acc[j] = 0.f;
        for (int g = 0; g < 10; ++g)
            fma40(x4[g], &Wv[g * 160], 40, acc);
#pragma unroll
        for (int j = 0; j < 40; ++j) VT[j * KT_STRIDE + t] = acc[j];
    }
    __syncthreads();

    // ---- kv-reduce: 40 (h,e) pairs, 20 per wave (spread across both waves)
    {
        int lane = t & 63, wid = t >> 6;
        if (lane < 20) {
            int idx = wid * 20 + lane;          // (h*5+e) = idx
            int h = idx / 5;
            float ks = 0.f;
            float kv0 = 0.f, kv1 = 0.f, kv2 = 0.f, kv3 = 0.f, kv4 = 0.f;
            const float* kr = &KT[idx * KT_STRIDE];
            const float* v0 = &VT[(h * 5 + 0) * KT_STRIDE];
            const float* v1 = &VT[(h * 5 + 1) * KT_STRIDE];
            const float* v2 = &VT[(h * 5 + 2) * KT_STRIDE];
            const float* v3 = &VT[(h * 5 + 3) * KT_STRIDE];
            const float* v4 = &VT[(h * 5 + 4) * KT_STRIDE];
            for (int s = 0; s < 128; s += 4) {
                float4 K4 = *(const float4*)&kr[s];
                float4 A = *(const float4*)&v0[s];
                float4 B = *(const float4*)&v1[s];
                float4 C = *(const float4*)&v2[s];
                float4 D = *(const float4*)&v3[s];
                float4 E = *(const float4*)&v4[s];
                ks  += K4.x + K4.y + K4.z + K4.w;
                kv0 += K4.x*A.x + K4.y*A.y + K4.z*A.z + K4.w*A.w;
                kv1 += K4.x*B.x + K4.y*B.y + K4.z*B.z + K4.w*B.w;
                kv2 += K4.x*C.x + K4.y*C.y + K4.z*C.z + K4.w*C.w;
                kv3 += K4.x*D.x + K4.y*D.y + K4.z*D.z + K4.w*D.w;
                kv4 += K4.x*E.x + K4.y*E.y + K4.z*E.z + K4.w*E.w;
            }
            ksb[idx] = ks;
            kvb[idx * 5 + 0] = kv0; kvb[idx * 5 + 1] = kv1;
            kvb[idx * 5 + 2] = kv2; kvb[idx * 5 + 3] = kv3;
            kvb[idx * 5 + 4] = kv4;
        }
    }
    __syncthreads();

    // ---- Q, attention, @Wm, LN1 -> msg   (all per-thread)
    float o[40];
    {
        float q[40];
#pragma unroll
        for (int j = 0; j < 40; ++j) q[j] = 0.f;
        for (int g = 0; g < 10; ++g)
            fma40(x4[g], &Wq[g * 160], 40, q);
#pragma unroll
        for (int j = 0; j < 40; ++j) q[j] = elup1(q[j]);

#pragma unroll
        for (int h = 0; h < 8; ++h) {
            float den = 1e-6f;
#pragma unroll
            for (int e = 0; e < 5; ++e) den += q[h*5+e] * ksb[h*5+e];
            float inv = 1.f / den;
#pragma unroll
            for (int d = 0; d < 5; ++d) {
                float val = 0.f;
#pragma unroll
                for (int e = 0; e < 5; ++e)
                    val += q[h*5+e] * kvb[(h*5+e)*5 + d];
                o[h*5+d] = val * inv;
            }
        }
    }
    // macc = o @ Wm
    float macc[40];
#pragma unroll
    for (int j = 0; j < 40; ++j) macc[j] = 0.f;
#pragma unroll
    for (int g = 0; g < 10; ++g) {
        float4 ov = make_float4(o[4*g], o[4*g+1], o[4*g+2], o[4*g+3]);
        fma40(ov, &Wm[g * 160], 40, macc);
    }
    // LN1
    {
        float s1 = 0.f, s2 = 0.f;
#pragma unroll
        for (int j = 0; j < 40; ++j) { s1 += macc[j]; s2 += macc[j] * macc[j]; }
        float mu = s1 * (1.f / 40.f);
        float va = s2 * (1.f / 40.f) - mu * mu;
        float rs = rsqrtf(va + 1e-5f);
#pragma unroll
        for (int j = 0; j < 40; ++j)
            macc[j] = (macc[j] - mu) * rs * g1[j] + b1[j];
    }
    float4* md = (float4*)(msg + ((size_t)r * 128 + t) * 40);
#pragma unroll
    for (int g = 0; g < 10; ++g)
        md[g] = make_float4(macc[4*g], macc[4*g+1], macc[4*g+2], macc[4*g+3]);
}

// ---------------------------------------------------------------------------
// K3b v2: layer-2 FFN, token-per-thread, ZERO LDS. h is consumed by the same
// thread so it never leaves registers. Two 40-col halves: hacc[40]+oacc[40].
// Weights wave-uniform -> s_load. LN2+residual fused into stores.
// ---------------------------------------------------------------------------
__global__ __launch_bounds__(128) void k3b_ffn(
    float* __restrict__ xr, const float* __restrict__ msg,
    const float* __restrict__ W1, const float* __restrict__ W2,
    const float* __restrict__ g2, const float* __restrict__ b2)
{
    int p = blockIdx.x * 128 + threadIdx.x;
    const float4* x4 = (const float4*)(xr + (size_t)p * 40);
    const float4* m4 = (const float4*)(msg + (size_t)p * 40);

    float oacc[40];
#pragma unroll
    for (int j = 0; j < 40; ++j) oacc[j] = 0.f;

#pragma unroll
    for (int half = 0; half < 2; ++half) {
        const int j0 = half * 40;
        float hacc[40];
#pragma unroll
        for (int j = 0; j < 40; ++j) hacc[j] = 0.f;
        for (int g = 0; g < 10; ++g)                  // x part (W1 rows 0..39)
            fma40(x4[g], &W1[(g * 4) * 80 + j0], 80, hacc);
        for (int g = 0; g < 10; ++g)                  // msg part (W1 rows 40..79)
            fma40(m4[g], &W1[(40 + g * 4) * 80 + j0], 80, hacc);
#pragma unroll
        for (int j = 0; j < 40; ++j) hacc[j] = fmaxf(hacc[j], 0.f);
#pragma unroll
        for (int g = 0; g < 10; ++g) {                // W2 rows j0..j0+39
            float4 hv = make_float4(hacc[4*g], hacc[4*g+1], hacc[4*g+2], hacc[4*g+3]);
            fma40(hv, &W2[(j0 + g * 4) * 40], 40, oacc);
        }
    }

    // LN2 + residual, fused into stores
    float s1 = 0.f, s2 = 0.f;
#pragma unroll
    for (int j = 0; j < 40; ++j) { s1 += oacc[j]; s2 += oacc[j] * oacc[j]; }
    float mu = s1 * (1.f / 40.f);
    float va = s2 * (1.f / 40.f) - mu * mu;
    float rs = rsqrtf(va + 1e-5f);

    float4* dst = (float4*)(xr + (size_t)p * 40);
#pragma unroll
    for (int g = 0; g < 10; ++g) {
        float4 xv = x4[g];
        float4 o4;
        o4.x = xv.x + (oacc[4*g+0] - mu) * rs * g2[4*g+0] + b2[4*g+0];
        o4.y = xv.y + (oacc[4*g+1] - mu) * rs * g2[4*g+1] + b2[4*g+1];
        o4.z = xv.z + (oacc[4*g+2] - mu) * rs * g2[4*g+2] + b2[4*g+2];
        o4.w = xv.w + (oacc[4*g+3] - mu) * rs * g2[4*g+3] + b2[4*g+3];
        dst[g] = o4;
    }
}

// ---------------------------------------------------------------------------
// K4: srdf head (unchanged)
// ---------------------------------------------------------------------------
__global__ __launch_bounds__(256) void k4_dm(
    const float* __restrict__ xr,
    const float* __restrict__ W1, const float* __restrict__ b1,
    const float* __restrict__ W2, const float* __restrict__ b2,
    const float* __restrict__ W3, const float* __restrict__ b3,
    float* __restrict__ out1)
{
    __shared__ float s[1857];
    int t = threadIdx.x;
    for (int i = t; i < 1280; i += 256) s[i] = W1[i];
    if (t < 32) s[1280 + t] = b1[t];
    for (int i = t; i < 512; i += 256) s[1312 + i] = W2[i];
    if (t < 16) { s[1824 + t] = b2[t]; s[1840 + t] = W3[t]; }
    if (t == 0) s[1856] = b3[0];
    __syncthreads();

    int p = blockIdx.x * 256 + t;
    float x[40];
    const float4* xp = (const float4*)(xr + (size_t)p * 40);
#pragma unroll
    for (int i = 0; i < 10; ++i) {
        float4 v4 = xp[i];
        x[4*i] = v4.x; x[4*i+1] = v4.y; x[4*i+2] = v4.z; x[4*i+3] = v4.w;
    }
    float h1[32];
#pragma unroll
    for (int j = 0; j < 32; ++j) h1[j] = s[1280 + j];
    for (int k = 0; k < 40; ++k) {
        float xv = x[k];
#pragma unroll
        for (int j = 0; j < 32; ++j) h1[j] += xv * s[k * 32 + j];
    }
#pragma unroll
    for (int j = 0; j < 32; ++j) h1[j] = fmaxf(h1[j], 0.f);
    float h2[16];
#pragma unroll
    for (int j = 0; j < 16; ++j) h2[j] = s[1824 + j];
    for (int k = 0; k < 32; ++k) {
        float hv = h1[k];
#pragma unroll
        for (int j = 0; j < 16; ++j) h2[j] += hv * s[1312 + k * 16 + j];
    }
    float o = s[1856];
#pragma unroll
    for (int j = 0; j < 16; ++j) o += fmaxf(h2[j], 0.f) * s[1840 + j];
    out1[p] = o;
}

// ---------------------------------------------------------------------------
// K5: rw head + masked softmax + radiance blend (unchanged)
// ---------------------------------------------------------------------------
__global__ __launch_bounds__(256) void k5_rw(
    const float* __restrict__ vf, const float* __restrict__ dirw,
    const float* __restrict__ maskw, const float* __restrict__ rgbw,
    const float* __restrict__ W1, const float* __restrict__ b1,
    const float* __restrict__ W2, const float* __restrict__ b2,
    const float* __restrict__ W3, const float* __restrict__ b3,
    float* __restrict__ out0)
{
    __shared__ float s[721];
    int t = threadIdx.x;
    for (int i = t; i < 560; i += 256) s[i] = W1[i];
    if (t < 16) s[560 + t] = b1[t];
    if (t < 128) s[576 + t] = W2[t];
    if (t < 8) { s[704 + t] = b2[t]; s[712 + t] = W3[t]; }
    if (t == 0) s[720] = b3[0];
    __syncthreads();

    int p = blockIdx.x * 256 + t;
    float xw[4];
#pragma unroll
    for (int v = 0; v < 4; ++v) {
        float in[35];
        const float4* vp = (const float4*)(vf + ((size_t)p * 4 + v) * 32);
#pragma unroll
        for (int q = 0; q < 8; ++q) {
            float4 f4 = vp[q];
            in[4*q] = f4.x; in[4*q+1] = f4.y; in[4*q+2] = f4.z; in[4*q+3] = f4.w;
        }
        in[32] = dirw[(size_t)p * 12 + v * 3 + 0];
        in[33] = dirw[(size_t)p * 12 + v * 3 + 1];
        in[34] = dirw[(size_t)p * 12 + v * 3 + 2];
        float h1[16];
#pragma unroll
        for (int j = 0; j < 16; ++j) h1[j] = s[560 + j];
        for (int k = 0; k < 35; ++k) {
            float xv = in[k];
#pragma unroll
            for (int j = 0; j < 16; ++j) h1[j] += xv * s[k * 16 + j];
        }
        float h2[8];
#pragma unroll
        for (int j = 0; j < 8; ++j) h2[j] = s[704 + j];
        for (int k = 0; k < 16; ++k) {
            float hv = fmaxf(h1[k], 0.f);
#pragma unroll
            for (int j = 0; j < 8; ++j) h2[j] += hv * s[576 + k * 8 + j];
        }
        float o = s[720];
#pragma unroll
        for (int j = 0; j < 8; ++j) o += fmaxf(h2[j], 0.f) * s[712 + j];
        xw[v] = (maskw[(size_t)p * 4 + v] == 0.f) ? -1e9f : o;
    }
    float m = fmaxf(fmaxf(xw[0], xw[1]), fmaxf(xw[2], xw[3]));
    float e0 = expf(xw[0] - m), e1 = expf(xw[1] - m), e2 = expf(xw[2] - m), e3 = expf(xw[3] - m);
    float inv = 1.f / (e0 + e1 + e2 + e3);
    float w4[4] = { e0 * inv, e1 * inv, e2 * inv, e3 * inv };
    float r0 = 0.f, r1 = 0.f, r2 = 0.f;
#pragma unroll
    for (int v = 0; v < 4; ++v) {
        r0 += rgbw[(size_t)p * 12 + v * 3 + 0] * w4[v];
        r1 += rgbw[(size_t)p * 12 + v * 3 + 1] * w4[v];
        r2 += rgbw[(size_t)p * 12 + v * 3 + 2] * w4[v];
    }
    out0[(size_t)p * 3 + 0] = r0;
    out0[(size_t)p * 3 + 1] = r1;
    out0[(size_t)p * 3 + 2] = r2;
}

// ---------------------------------------------------------------------------
extern "C" void kernel_launch(void* const* d_in, const int* in_sizes, int n_in,
                              void* d_out, int out_size, void* d_ws, size_t ws_size,
                              hipStream_t stream) {
    (void)in_sizes; (void)n_in; (void)out_size; (void)ws_size;
    const float* p3d   = (const float*)d_in[0];
    const float* imgs  = (const float*)d_in[1];
    const float* feat  = (const float*)d_in[2];
    const float* rpi   = (const float*)d_in[3];
    const float* spi   = (const float*)d_in[4];
    const float* sp    = (const float*)d_in[5];
    const float* vtok  = (const float*)d_in[6];
    const float* vtWq  = (const float*)d_in[7];
    const float* vtWk  = (const float*)d_in[8];
    const float* vtWv  = (const float*)d_in[9];
    const float* vtWm  = (const float*)d_in[10];
    const float* vtg1  = (const float*)d_in[11];
    const float* vtb1  = (const float*)d_in[12];
    const float* vtW1  = (const float*)d_in[13];
    const float* vtW2  = (const float*)d_in[14];
    const float* vtg2  = (const float*)d_in[15];
    const float* vtb2  = (const float*)d_in[16];
    const float* rtWq  = (const float*)d_in[17];
    const float* rtWk  = (const float*)d_in[18];
    const float* rtWv  = (const float*)d_in[19];
    const float* rtWm  = (const float*)d_in[20];
    const float* rtg1  = (const float*)d_in[21];
    const float* rtb1  = (const float*)d_in[22];
    const float* rtW1  = (const float*)d_in[23];
    const float* rtW2  = (const float*)d_in[24];
    const float* rtg2  = (const float*)d_in[25];
    const float* rtb2  = (const float*)d_in[26];
    const float* dmW1  = (const float*)d_in[27];
    const float* dmb1  = (const float*)d_in[28];
    const float* dmW2  = (const float*)d_in[29];
    const float* dmb2  = (const float*)d_in[30];
    const float* dmW3  = (const float*)d_in[31];
    const float* dmb3  = (const float*)d_in[32];
    const float* rwW1  = (const float*)d_in[33];
    const float* rwb1  = (const float*)d_in[34];
    const float* rwW2  = (const float*)d_in[35];
    const float* rwb2  = (const float*)d_in[36];
    const float* rwW3  = (const float*)d_in[37];
    const float* rwb3  = (const float*)d_in[38];

    float* out  = (float*)d_out;
    float* out0 = out;
    float* out1 = out + 393216;
    float* out2 = out + 524288;

    float* ws    = (float*)d_ws;
    float* featT = ws + WS_FEATT;
    float* imgT  = ws + WS_IMGT;
    float* x1    = ws + WS_X1;
    float* xr    = ws + WS_XR;
    float* msg   = ws + WS_MSG;
    float* rgbw  = ws + WS_RGB;
    float* dirw  = ws + WS_DIR;
    float* maskw = ws + WS_MASK;

    k0_transpose<<<dim3(1024), dim3(256), 0, stream>>>(feat, imgs, featT, imgT);
    k1_geom_sample<<<dim3(2048), dim3(256), 0, stream>>>(p3d, rpi, spi, sp, featT, imgT,
                                                         x1, rgbw, dirw, maskw, out2);
    k2_loftr1<<<dim3(K2_GRID), dim3(K2_BLK), 0, stream>>>(x1, vtok, vtWq, vtWk, vtWv, vtWm,
                                                    vtg1, vtb1, vtW1, vtW2, vtg2, vtb2, xr);
    k3a_attn<<<dim3(1024), dim3(128), 0, stream>>>(xr, rtWq, rtWk, rtWv, rtWm, rtg1, rtb1, msg);
    k3b_ffn<<<dim3(1024), dim3(128), 0, stream>>>(xr, msg, rtW1, rtW2, rtg2, rtb2);
    k4_dm<<<dim3(512), dim3(256), 0, stream>>>(xr, dmW1, dmb1, dmW2, dmb2, dmW3, dmb3, out1);
    k5_rw<<<dim3(512), dim3(256), 0, stream>>>(x1, dirw, maskw, rgbw,
                                               rwW1, rwb1, rwW2, rwb2, rwW3, rwb3, out0);
}